// Round 4
// baseline (506.398 us; speedup 1.0000x reference)
//
#include <hip/hip_runtime.h>

// ---------------- constants ----------------
#define BATCH 2
#define SEQ   2048
#define HID   2048
#define NH    16
#define DN    128
#define DR    64
#define DV    128
#define RANK  512
#define DQK   192            // DN + DR
#define NQ    (NH*DQK)       // 3072
#define NQKV  3712           // NQ + 640 (kv_a padded)
#define NKVB  (NH*(DN+DV))   // 4096
#define NTOK  (BATCH*SEQ)    // 4096
#define SCALE_F 0.07216878364870323f  // 192^-0.5
#define SCALE_LOG2E 0.10411754831420211f  // SCALE_F * log2(e)

typedef __bf16 bf16x8 __attribute__((ext_vector_type(8)));
typedef float  f32x4  __attribute__((ext_vector_type(4)));
typedef unsigned int u32x4 __attribute__((ext_vector_type(4)));
typedef unsigned short u16;
typedef unsigned short u16x4 __attribute__((ext_vector_type(4)));

__device__ __forceinline__ float b2f(u16 h) {
    unsigned int u = ((unsigned int)h) << 16;
    float f; __builtin_memcpy(&f, &u, 4); return f;
}
__device__ __forceinline__ u16 f2b(float f) {
    unsigned int x; __builtin_memcpy(&x, &f, 4);
    unsigned int r = x + 0x7fffu + ((x >> 16) & 1u);
    return (u16)(r >> 16);
}
__device__ __forceinline__ bf16x8 lds_frag(const u16* p) {
    u32x4 v = *(const u32x4*)p;
    return __builtin_bit_cast(bf16x8, v);
}
__device__ __forceinline__ bf16x8 to_frag(u32x4 v) {
    return __builtin_bit_cast(bf16x8, v);
}
__device__ __forceinline__ f32x4 mfma16(bf16x8 a, bf16x8 b, f32x4 c) {
    return __builtin_amdgcn_mfma_f32_16x16x32_bf16(a, b, c, 0, 0, 0);
}
__device__ __forceinline__ void store_out(u16* p, float v) { *p = f2b(v); }
__device__ __forceinline__ void store_out(float* p, float v) { *p = v; }
__device__ __forceinline__ void gld_lds16(const u16* g, u16* l) {
    __builtin_amdgcn_global_load_lds(
        (const __attribute__((address_space(1))) unsigned int*)g,
        (__attribute__((address_space(3))) unsigned int*)l, 16, 0, 0);
}

// ---------------- fused prep: hs cast + 4 weight transposes, one launch ----------
__global__ __launch_bounds__(256) void prep_kernel(
        const float* __restrict__ hs_f, u16* __restrict__ hs,
        const float* __restrict__ Wq, const float* __restrict__ Wkva,
        const float* __restrict__ Wkvb, const float* __restrict__ Wout,
        u16* __restrict__ WqkvT, u16* __restrict__ WkvbT, u16* __restrict__ WoutT) {
    int tid = threadIdx.x;
    int bid = blockIdx.x;
    if (bid < 8192) {            // cast: 8192*256 f32x4 = NTOK*HID elems
        int i = bid * 256 + tid;
        f32x4 v = *(const f32x4*)(hs_f + (size_t)i * 4);
        u16 o[4];
        for (int k = 0; k < 4; k++) o[k] = f2b(v[k]);
        *(unsigned long long*)(hs + (size_t)i * 4) = *(unsigned long long*)o;
        return;
    }
    bid -= 8192;
    const float* in; u16* out; int R, C, tilesC;
    if (bid < 1536)      { in = Wq;   out = WqkvT;                       R = HID;  C = NQ;   tilesC = 48; }
    else if (bid < 1856) { bid -= 1536; in = Wkva; out = WqkvT + (size_t)NQ * HID; R = HID; C = 576; tilesC = 10; }
    else if (bid < 2368) { bid -= 1856; in = Wkvb; out = WkvbT;          R = RANK; C = NKVB; tilesC = 64; }
    else                 { bid -= 2368; in = Wout; out = WoutT;          R = HID;  C = HID;  tilesC = 32; }
    __shared__ unsigned int t32[64 * 65];
    int r0 = (bid / tilesC) * 64, c0 = (bid % tilesC) * 64;
    bool valid = (c0 < C);
    for (int i = 0; i < 4; i++) {
        int u = tid + i * 256;
        int rl = u >> 4, c4 = u & 15;
        f32x4 v = {0.f, 0.f, 0.f, 0.f};
        if (valid) v = *(const f32x4*)&in[(size_t)(r0 + rl) * C + c0 + c4 * 4];
        for (int j = 0; j < 4; j++)
            t32[(c4 * 4 + j) * 65 + rl] = f2b(v[j]);
    }
    __syncthreads();
    for (int i = 0; i < 2; i++) {
        int u = tid + i * 256;
        int cl = u >> 3, r8 = (u & 7) * 8;
        unsigned int w[8];
        for (int j = 0; j < 8; j++) w[j] = t32[cl * 65 + r8 + j];
        u32x4 pk;
        for (int j = 0; j < 4; j++) pk[j] = (w[2 * j] & 0xffffu) | (w[2 * j + 1] << 16);
        *(u32x4*)&out[(size_t)(c0 + cl) * R + r0 + r8] = pk;
    }
}

// ---------------- generic bf16 GEMM: C[M,N] = A[M,K] * Bt[N,K]^T (m97 pattern) ----
template <typename OutT>
__global__ __launch_bounds__(256) void gemm_bt(const u16* __restrict__ A,
                                               const u16* __restrict__ Bt,
                                               OutT* __restrict__ C,
                                               int K, int lda, int ldb, int ldc) {
    __shared__ u16 As[128 * 32];
    __shared__ u16 Bs[128 * 32];
    int tid = threadIdx.x, lane = tid & 63, w = tid >> 6;
    int wm = (w >> 1) * 64, wn = (w & 1) * 64;
    int g = lane >> 4, ln = lane & 15;
    int m0 = blockIdx.y * 128, n0 = blockIdx.x * 128;
    f32x4 acc[4][4] = {};
    for (int k0 = 0; k0 < K; k0 += 32) {
        for (int i = 0; i < 2; i++) {
            int ch = tid + i * 256;
            int row = ch >> 2, o = ch & 3;
            gld_lds16(&A[(size_t)(m0 + row) * lda + k0 + o * 8], &As[row * 32 + o * 8]);
            gld_lds16(&Bt[(size_t)(n0 + row) * ldb + k0 + o * 8], &Bs[row * 32 + o * 8]);
        }
        __syncthreads();
        bf16x8 af[4], bf[4];
        for (int i = 0; i < 4; i++) af[i] = lds_frag(&As[(wm + i * 16 + ln) * 32 + g * 8]);
        for (int j = 0; j < 4; j++) bf[j] = lds_frag(&Bs[(wn + j * 16 + ln) * 32 + g * 8]);
        for (int i = 0; i < 4; i++)
            for (int j = 0; j < 4; j++)
                acc[i][j] = mfma16(af[i], bf[j], acc[i][j]);
        __syncthreads();
    }
    for (int i = 0; i < 4; i++)
        for (int j = 0; j < 4; j++)
            for (int r = 0; r < 4; r++) {
                int m = m0 + wm + i * 16 + g * 4 + r;
                int n = n0 + wn + j * 16 + ln;
                store_out(&C[(size_t)m * ldc + n], acc[i][j][r]);
            }
}

// ---------------- RoPE on q (in-place on qkv, last 64 of each head's 192) --------
__global__ void rope_q(u16* __restrict__ qkv, const float* __restrict__ freqs) {
    int token = blockIdx.x;
    int s = token & (SEQ - 1);
    int tid = threadIdx.x;
    for (int i = 0; i < 2; i++) {
        int idx = tid + i * 256;          // 512 pairs = 16 heads * 32
        int hh = idx >> 5, p = idx & 31;
        float th = freqs[s * 32 + p];
        float c = __cosf(th), sn = __sinf(th);
        size_t off = (size_t)token * NQKV + hh * DQK + DN + 2 * p;
        float x1 = b2f(qkv[off]), x2 = b2f(qkv[off + 1]);
        qkv[off]     = f2b(x1 * c - x2 * sn);
        qkv[off + 1] = f2b(x1 * sn + x2 * c);
    }
}

// ---------------- LayerNorm over RANK cols of qkv (cols NQ..NQ+511) --------------
__global__ void ln_kv(const u16* __restrict__ qkv, const float* __restrict__ gamma,
                      const float* __restrict__ beta, u16* __restrict__ kv_c) {
    int row = blockIdx.x, tid = threadIdx.x;
    size_t base = (size_t)row * NQKV + NQ;
    float x0 = b2f(qkv[base + tid]), x1 = b2f(qkv[base + 256 + tid]);
    float s = x0 + x1, q2 = x0 * x0 + x1 * x1;
    for (int o = 32; o > 0; o >>= 1) { s += __shfl_xor(s, o); q2 += __shfl_xor(q2, o); }
    __shared__ float sh[8];
    int lane = tid & 63, w = tid >> 6;
    if (lane == 0) { sh[w] = s; sh[4 + w] = q2; }
    __syncthreads();
    float S = sh[0] + sh[1] + sh[2] + sh[3];
    float Q2 = sh[4] + sh[5] + sh[6] + sh[7];
    float mu = S * (1.f / 512.f);
    float var = Q2 * (1.f / 512.f) - mu * mu;
    float rs = rsqrtf(var + 1e-5f);
    kv_c[(size_t)row * RANK + tid] =
        f2b((x0 - mu) * rs * gamma[tid] + beta[tid]);
    kv_c[(size_t)row * RANK + 256 + tid] =
        f2b((x1 - mu) * rs * gamma[256 + tid] + beta[256 + tid]);
}

// ---------------- assemble K in MFMA-FRAGMENT order -------------------------------
// Kf layout: [b][h][kt=32][kk=6][r=64][c=32] (u16), element = K[s=kt*64+r][d=kk*32+c]
// Per (b,h): 32*6*64*32 = 393216 u16 (= 32 tiles * 12288).
// attn reads af[mi][kk] as ONE coalesced 1KB global_load_dwordx4 per instruction:
// lane(g,ln) addr = tile + kk*2048 + (w2*32+mi*16+ln)*32 + g*8 -> ln*64B + g*16B.
__global__ void k_assemble(const u16* __restrict__ kvb, const u16* __restrict__ qkv,
                           const float* __restrict__ freqs, u16* __restrict__ Kf) {
    int token = blockIdx.x;
    int b = token >> 11;              // SEQ = 2048
    int s = token & (SEQ - 1);
    int tid = threadIdx.x;
    __shared__ u16 roped[64];
    if (tid < 32) {
        int p = tid;
        float th = freqs[s * 32 + p];
        float c = __cosf(th), sn = __sinf(th);
        float x1 = b2f(qkv[(size_t)token * NQKV + NQ + RANK + 2 * p]);
        float x2 = b2f(qkv[(size_t)token * NQKV + NQ + RANK + 2 * p + 1]);
        roped[2 * p]     = f2b(x1 * c - x2 * sn);
        roped[2 * p + 1] = f2b(x1 * sn + x2 * c);
    }
    __syncthreads();
    int kt = s >> 6, r = s & 63;
    {   // k_nope: 16 heads x 16 chunks of 8 u16; d = c8 in [0,128): kk = c8>>5
        int hh = tid >> 4, c8 = (tid & 15) * 8;
        size_t dst = ((size_t)(b * NH + hh) * 32 + kt) * 12288
                   + (size_t)(c8 >> 5) * 2048 + r * 32 + (c8 & 31);
        *(u32x4*)&Kf[dst] = *(const u32x4*)&kvb[(size_t)token * NKVB + hh * 256 + c8];
    }
    if (tid < 128) {  // rope broadcast: d = 128 + c8 -> kk = 4 + (c8>>5)
        int hh = tid >> 3, c8 = (tid & 7) * 8;
        size_t dst = ((size_t)(b * NH + hh) * 32 + kt) * 12288
                   + (size_t)(4 + (c8 >> 5)) * 2048 + r * 32 + (c8 & 31);
        *(u32x4*)&Kf[dst] = *(u32x4*)&roped[c8];
    }
}

// ---------------- V transpose into MFMA-FRAGMENT order ----------------------------
// Vt layout: [b][h][st=32][kk=2][dr=128][c=32] (u16), element = V[s=st*64+kk*32+c][dr]
// Per (b,h): 32*2*128*32 = 262144 u16 (= 32 tiles * 8192).
__global__ void v_transpose(const u16* __restrict__ kvb, u16* __restrict__ Vt) {
    __shared__ unsigned int t32[64 * 65];
    int bx = blockIdx.x;              // s-tile (64 rows)
    int st = bx * 64, dt = blockIdx.y * 64;
    int b = blockIdx.z >> 4, h = blockIdx.z & 15;
    int tid = threadIdx.x;
    for (int i = 0; i < 2; i++) {
        int u = tid + i * 256;
        int sl = u >> 3, c8 = (u & 7) * 8;
        u32x4 v = *(const u32x4*)&kvb[((size_t)(b * SEQ + st + sl) * NH + h) * 256 + DN + dt + c8];
        for (int j = 0; j < 4; j++) {
            t32[(c8 + 2 * j) * 65 + sl]     = v[j] & 0xffffu;
            t32[(c8 + 2 * j + 1) * 65 + sl] = v[j] >> 16;
        }
    }
    __syncthreads();
    for (int i = 0; i < 2; i++) {
        int u = tid + i * 256;
        int dl = u >> 3, s8 = (u & 7) * 8;     // within-tile s offset, multiple of 8
        unsigned int w[8];
        for (int j = 0; j < 8; j++) w[j] = t32[dl * 65 + s8 + j];
        u32x4 pk;
        for (int j = 0; j < 4; j++) pk[j] = (w[2 * j] & 0xffffu) | (w[2 * j + 1] << 16);
        size_t dst = ((size_t)(b * NH + h) * 32 + bx) * 8192
                   + (size_t)(s8 >> 5) * 4096 + (size_t)(dt + dl) * 32 + (s8 & 31);
        *(u32x4*)&Vt[dst] = pk;
    }
}

// ---------------- flash attention v4: direct-fragment K/V, P-only LDS -------------
// K and V are read straight from global in fragment order (1KB coalesced per
// instruction, L2-resident per-XCD via the swizzle below) -> no K/V staging, no
// stage barriers. LDS holds only a DOUBLE-BUFFERED P (2x9KB) + lsum -> ONE
// __syncthreads per K-tile (dbuf removes the anti-dependence barrier; the
// lgkmcnt(0) drain at each barrier orders P reads of iter t before P writes of
// iter t+2). Grid flattened to 1D and XCD-swizzled: 1024 blocks, each XCD owns
// 4 whole heads so its K/V (4 x 1.3MB) stays in its private L2.
#define KC    64
#define QTILE 64
#define PSTR 72
#define NIT  (SEQ / KC)
__global__ __launch_bounds__(256, 4) void attn_kernel(const u16* __restrict__ Q,
                                                      const u16* __restrict__ Kf,
                                                      const u16* __restrict__ Vt,
                                                      u16* __restrict__ O) {
    __shared__ u16 Ps[2][QTILE * PSTR];  // 18.4 KB double-buffered P[q][kv]
    __shared__ float lsumLDS[2][QTILE];
    int tid = threadIdx.x, lane = tid & 63, w = tid >> 6;
    int w1 = w & 1;    // q 32-half
    int w2 = w >> 1;   // kv 32-half (QK) / d 64-half (PV)
    int g = lane >> 4, ln = lane & 15;
    // XCD-bijective swizzle (1024 % 8 == 0): XCD x gets contiguous work chunk
    int bid = blockIdx.x;
    int swz = ((bid & 7) << 7) | (bid >> 3);
    int qt = swz & 31, h = (swz >> 5) & 15, b = swz >> 9;

    size_t qbase = ((size_t)(b * SEQ + qt * QTILE)) * NQKV + h * DQK;
    const u16* Kh = Kf + (size_t)(b * NH + h) * (32 * 12288);
    const u16* Vh = Vt + (size_t)(b * NH + h) * (32 * 8192);

    // Q fragments -> registers (pre-roped in memory by rope_q)
    bf16x8 bfq[2][6];
    for (int ni = 0; ni < 2; ni++)
        for (int kk = 0; kk < 6; kk++)
            bfq[ni][kk] = to_frag(*(const u32x4*)&Q[qbase +
                (size_t)(w1 * 32 + ni * 16 + ln) * NQKV + kk * 32 + g * 8]);

    f32x4 oacc[2][4] = {};
    float lpriv[2] = {0.f, 0.f};
    int arow = (w2 * 32 + ln) * 32 + g * 8;   // K frag lane offset (+ mi*512)
    int vrow = (w2 * 64 + ln) * 32 + g * 8;   // V frag lane offset (+ ni*512)

    for (int kt = 0; kt < NIT; kt++) {
        // S^T[kv][q] = K . Q^T, K fragments direct from global (coalesced 1KB)
        const u16* kT = Kh + (size_t)kt * 12288;
        f32x4 sacc[2][2] = {};
        for (int kk = 0; kk < 6; kk++) {
            bf16x8 af[2];
            for (int mi = 0; mi < 2; mi++)
                af[mi] = to_frag(*(const u32x4*)&kT[kk * 2048 + mi * 512 + arow]);
            for (int mi = 0; mi < 2; mi++)
                for (int ni = 0; ni < 2; ni++)
                    sacc[mi][ni] = mfma16(af[mi], bfq[ni][kk], sacc[mi][ni]);
        }
        // exp2 + private row-sum + packed b64 P store (cvt_pk) into Ps[kt&1]
        u16* Psb = Ps[kt & 1];
        for (int mi = 0; mi < 2; mi++)
            for (int ni = 0; ni < 2; ni++) {
                float p0 = exp2f(sacc[mi][ni][0] * SCALE_LOG2E);
                float p1 = exp2f(sacc[mi][ni][1] * SCALE_LOG2E);
                float p2 = exp2f(sacc[mi][ni][2] * SCALE_LOG2E);
                float p3 = exp2f(sacc[mi][ni][3] * SCALE_LOG2E);
                lpriv[ni] += (p0 + p1) + (p2 + p3);
                unsigned int q0, q1;
                asm("v_cvt_pk_bf16_f32 %0, %1, %2" : "=v"(q0) : "v"(p0), "v"(p1));
                asm("v_cvt_pk_bf16_f32 %0, %1, %2" : "=v"(q1) : "v"(p2), "v"(p3));
                uint2 pk; pk.x = q0; pk.y = q1;
                *(uint2*)&Psb[(w1 * 32 + ni * 16 + ln) * PSTR + (w2 * 32 + mi * 16 + g * 4)] = pk;
            }
        __syncthreads();   // single barrier: P[kt&1] ready (dbuf covers anti-dep)
        // O[q][d] += P . V, V fragments direct from global (coalesced 1KB)
        const u16* vT = Vh + (size_t)kt * 8192;
        for (int kk = 0; kk < 2; kk++) {
            bf16x8 pa[2], vb[4];
            for (int mi = 0; mi < 2; mi++)
                pa[mi] = lds_frag(&Psb[(w1 * 32 + mi * 16 + ln) * PSTR + kk * 32 + g * 8]);
            for (int ni = 0; ni < 4; ni++)
                vb[ni] = to_frag(*(const u32x4*)&vT[kk * 4096 + ni * 512 + vrow]);
            for (int mi = 0; mi < 2; mi++)
                for (int ni = 0; ni < 4; ni++)
                    oacc[mi][ni] = mfma16(pa[mi], vb[ni], oacc[mi][ni]);
        }
    }

    // final lsum reduction
    for (int ni = 0; ni < 2; ni++) {
        float v = lpriv[ni];
        v += __shfl_xor(v, 16);
        v += __shfl_xor(v, 32);
        if (g == 0) lsumLDS[w2][w1 * 32 + ni * 16 + ln] = v;
    }
    __syncthreads();
    for (int mi = 0; mi < 2; mi++)
        for (int ni = 0; ni < 4; ni++) {
            int d = w2 * 64 + ni * 16 + ln;
            for (int r = 0; r < 4; r++) {
                int row = w1 * 32 + mi * 16 + g * 4 + r;
                float l = lsumLDS[0][row] + lsumLDS[1][row];
                O[((size_t)(b * SEQ + qt * QTILE + row) * NH + h) * DV + d] =
                    f2b(oacc[mi][ni][r] / l);
            }
        }
}

// ---------------- launcher ----------------
extern "C" void kernel_launch(void* const* d_in, const int* in_sizes, int n_in,
                              void* d_out, int out_size, void* d_ws, size_t ws_size,
                              hipStream_t stream) {
    const float* hs_f  = (const float*)d_in[0];
    const float* freqs = (const float*)d_in[1];
    const float* Wq    = (const float*)d_in[2];
    const float* Wkva  = (const float*)d_in[3];
    const float* gamma = (const float*)d_in[4];
    const float* beta  = (const float*)d_in[5];
    const float* Wkvb  = (const float*)d_in[6];
    const float* Wout  = (const float*)d_in[7];
    float* outp = (float*)d_out;

    char* ws = (char*)d_ws;
    size_t off = 0;
    auto alloc = [&](size_t elems) -> u16* {
        u16* p = (u16*)(ws + off);
        off += ((elems * 2 + 255) / 256) * 256;
        return p;
    };
    u16* hs     = alloc((size_t)NTOK * HID);
    u16* WqkvT  = alloc((size_t)NQKV * HID);     // rows 0..3071 Wq^T, 3072..3711 Wkva^T (padded)
    u16* WkvbT  = alloc((size_t)NKVB * RANK);
    u16* WoutT  = alloc((size_t)HID * HID);
    u16* qkv    = alloc((size_t)NTOK * NQKV);    // q | kv_a output
    u16* kv_c   = alloc((size_t)NTOK * RANK);
    u16* kvb    = alloc((size_t)NTOK * NKVB);
    u16* Kf     = alloc((size_t)NTOK * NQ);      // fragment-order K (same elem count)
    u16* Vt     = alloc((size_t)BATCH * NH * DV * SEQ);  // fragment-order V^T
    u16* attn   = alloc((size_t)NTOK * NH * DV);
    (void)ws_size; (void)in_sizes; (void)n_in; (void)out_size;

    // 1. fused prep: cast + all weight transposes
    prep_kernel<<<8192 + 1536 + 320 + 512 + 1024, 256, 0, stream>>>(
        hs_f, hs, Wq, Wkva, Wkvb, Wout, WqkvT, WkvbT, WoutT);

    // 2. fused q + kv_a GEMM: (4096 x 3712 x 2048)
    gemm_bt<<<dim3(NQKV / 128, NTOK / 128), 256, 0, stream>>>(hs, WqkvT, qkv, HID, HID, HID, NQKV);

    // 3. RoPE on q (in place)
    rope_q<<<NTOK, 256, 0, stream>>>(qkv, freqs);

    // 4. layernorm
    ln_kv<<<NTOK, 256, 0, stream>>>(qkv, gamma, beta, kv_c);

    // 5. kvb = kv_c @ Wkv_b (4096 x 4096 x 512)
    gemm_bt<<<dim3(NKVB / 128, NTOK / 128), 256, 0, stream>>>(kv_c, WkvbT, kvb, RANK, RANK, RANK, NKVB);

    // 6. K assembly (fragment-order)
    k_assemble<<<NTOK, 256, 0, stream>>>(kvb, qkv, freqs, Kf);

    // 7. V transpose (fragment-order)
    v_transpose<<<dim3(SEQ / 64, DV / 64, BATCH * NH), 256, 0, stream>>>(kvb, Vt);

    // 8. attention (direct-fragment K/V, 1 barrier/iter, XCD-swizzled 1D grid)
    attn_kernel<<<1024, 256, 0, stream>>>(qkv, Kf, Vt, attn);

    // 9. out = attn @ Wout (4096 x 2048 x 2048)
    gemm_bt<<<dim3(HID / 128, NTOK / 128), 256, 0, stream>>>(attn, WoutT, outp, HID, HID, HID, HID);
}

// Round 5
// 479.849 us; speedup vs baseline: 1.0553x; 1.0553x over previous
//
#include <hip/hip_runtime.h>

// ---------------- constants ----------------
#define BATCH 2
#define SEQ   2048
#define HID   2048
#define NH    16
#define DN    128
#define DR    64
#define DV    128
#define RANK  512
#define DQK   192            // DN + DR
#define NQ    (NH*DQK)       // 3072
#define NQKV  3712           // NQ + 640 (kv_a padded)
#define NKVB  (NH*(DN+DV))   // 4096
#define NTOK  (BATCH*SEQ)    // 4096
#define SCALE_F 0.07216878364870323f  // 192^-0.5
#define SCALE_LOG2E 0.10411754831420211f  // SCALE_F * log2(e)

typedef __bf16 bf16x8 __attribute__((ext_vector_type(8)));
typedef float  f32x4  __attribute__((ext_vector_type(4)));
typedef unsigned int u32x4 __attribute__((ext_vector_type(4)));
typedef unsigned short u16;
typedef unsigned short u16x4 __attribute__((ext_vector_type(4)));

__device__ __forceinline__ float b2f(u16 h) {
    unsigned int u = ((unsigned int)h) << 16;
    float f; __builtin_memcpy(&f, &u, 4); return f;
}
__device__ __forceinline__ u16 f2b(float f) {
    unsigned int x; __builtin_memcpy(&x, &f, 4);
    unsigned int r = x + 0x7fffu + ((x >> 16) & 1u);
    return (u16)(r >> 16);
}
__device__ __forceinline__ bf16x8 lds_frag(const u16* p) {
    u32x4 v = *(const u32x4*)p;
    return __builtin_bit_cast(bf16x8, v);
}
__device__ __forceinline__ bf16x8 to_frag(u32x4 v) {
    return __builtin_bit_cast(bf16x8, v);
}
__device__ __forceinline__ f32x4 mfma16(bf16x8 a, bf16x8 b, f32x4 c) {
    return __builtin_amdgcn_mfma_f32_16x16x32_bf16(a, b, c, 0, 0, 0);
}
__device__ __forceinline__ void store_out(u16* p, float v) { *p = f2b(v); }
__device__ __forceinline__ void store_out(float* p, float v) { *p = v; }
__device__ __forceinline__ void gld_lds16(const u16* g, u16* l) {
    __builtin_amdgcn_global_load_lds(
        (const __attribute__((address_space(1))) unsigned int*)g,
        (__attribute__((address_space(3))) unsigned int*)l, 16, 0, 0);
}

// ---------------- fused prep: hs cast + 4 weight transposes, one launch ----------
__global__ __launch_bounds__(256) void prep_kernel(
        const float* __restrict__ hs_f, u16* __restrict__ hs,
        const float* __restrict__ Wq, const float* __restrict__ Wkva,
        const float* __restrict__ Wkvb, const float* __restrict__ Wout,
        u16* __restrict__ WqkvT, u16* __restrict__ WkvbT, u16* __restrict__ WoutT) {
    int tid = threadIdx.x;
    int bid = blockIdx.x;
    if (bid < 8192) {            // cast: 8192*256 f32x4 = NTOK*HID elems
        int i = bid * 256 + tid;
        f32x4 v = *(const f32x4*)(hs_f + (size_t)i * 4);
        u16 o[4];
        for (int k = 0; k < 4; k++) o[k] = f2b(v[k]);
        *(unsigned long long*)(hs + (size_t)i * 4) = *(unsigned long long*)o;
        return;
    }
    bid -= 8192;
    const float* in; u16* out; int R, C, tilesC;
    if (bid < 1536)      { in = Wq;   out = WqkvT;                       R = HID;  C = NQ;   tilesC = 48; }
    else if (bid < 1856) { bid -= 1536; in = Wkva; out = WqkvT + (size_t)NQ * HID; R = HID; C = 576; tilesC = 10; }
    else if (bid < 2368) { bid -= 1856; in = Wkvb; out = WkvbT;          R = RANK; C = NKVB; tilesC = 64; }
    else                 { bid -= 2368; in = Wout; out = WoutT;          R = HID;  C = HID;  tilesC = 32; }
    __shared__ unsigned int t32[64 * 65];
    int r0 = (bid / tilesC) * 64, c0 = (bid % tilesC) * 64;
    bool valid = (c0 < C);
    for (int i = 0; i < 4; i++) {
        int u = tid + i * 256;
        int rl = u >> 4, c4 = u & 15;
        f32x4 v = {0.f, 0.f, 0.f, 0.f};
        if (valid) v = *(const f32x4*)&in[(size_t)(r0 + rl) * C + c0 + c4 * 4];
        for (int j = 0; j < 4; j++)
            t32[(c4 * 4 + j) * 65 + rl] = f2b(v[j]);
    }
    __syncthreads();
    for (int i = 0; i < 2; i++) {
        int u = tid + i * 256;
        int cl = u >> 3, r8 = (u & 7) * 8;
        unsigned int w[8];
        for (int j = 0; j < 8; j++) w[j] = t32[cl * 65 + r8 + j];
        u32x4 pk;
        for (int j = 0; j < 4; j++) pk[j] = (w[2 * j] & 0xffffu) | (w[2 * j + 1] << 16);
        *(u32x4*)&out[(size_t)(c0 + cl) * R + r0 + r8] = pk;
    }
}

// ---------------- generic bf16 GEMM: C[M,N] = A[M,K] * Bt[N,K]^T (m97 pattern) ----
template <typename OutT>
__global__ __launch_bounds__(256) void gemm_bt(const u16* __restrict__ A,
                                               const u16* __restrict__ Bt,
                                               OutT* __restrict__ C,
                                               int K, int lda, int ldb, int ldc) {
    __shared__ u16 As[128 * 32];
    __shared__ u16 Bs[128 * 32];
    int tid = threadIdx.x, lane = tid & 63, w = tid >> 6;
    int wm = (w >> 1) * 64, wn = (w & 1) * 64;
    int g = lane >> 4, ln = lane & 15;
    int m0 = blockIdx.y * 128, n0 = blockIdx.x * 128;
    f32x4 acc[4][4] = {};
    for (int k0 = 0; k0 < K; k0 += 32) {
        for (int i = 0; i < 2; i++) {
            int ch = tid + i * 256;
            int row = ch >> 2, o = ch & 3;
            gld_lds16(&A[(size_t)(m0 + row) * lda + k0 + o * 8], &As[row * 32 + o * 8]);
            gld_lds16(&Bt[(size_t)(n0 + row) * ldb + k0 + o * 8], &Bs[row * 32 + o * 8]);
        }
        __syncthreads();
        bf16x8 af[4], bf[4];
        for (int i = 0; i < 4; i++) af[i] = lds_frag(&As[(wm + i * 16 + ln) * 32 + g * 8]);
        for (int j = 0; j < 4; j++) bf[j] = lds_frag(&Bs[(wn + j * 16 + ln) * 32 + g * 8]);
        for (int i = 0; i < 4; i++)
            for (int j = 0; j < 4; j++)
                acc[i][j] = mfma16(af[i], bf[j], acc[i][j]);
        __syncthreads();
    }
    for (int i = 0; i < 4; i++)
        for (int j = 0; j < 4; j++)
            for (int r = 0; r < 4; r++) {
                int m = m0 + wm + i * 16 + g * 4 + r;
                int n = n0 + wn + j * 16 + ln;
                store_out(&C[(size_t)m * ldc + n], acc[i][j][r]);
            }
}

// ---------------- RoPE on q (in-place on qkv, last 64 of each head's 192) --------
__global__ void rope_q(u16* __restrict__ qkv, const float* __restrict__ freqs) {
    int token = blockIdx.x;
    int s = token & (SEQ - 1);
    int tid = threadIdx.x;
    for (int i = 0; i < 2; i++) {
        int idx = tid + i * 256;          // 512 pairs = 16 heads * 32
        int hh = idx >> 5, p = idx & 31;
        float th = freqs[s * 32 + p];
        float c = __cosf(th), sn = __sinf(th);
        size_t off = (size_t)token * NQKV + hh * DQK + DN + 2 * p;
        float x1 = b2f(qkv[off]), x2 = b2f(qkv[off + 1]);
        qkv[off]     = f2b(x1 * c - x2 * sn);
        qkv[off + 1] = f2b(x1 * sn + x2 * c);
    }
}

// ---------------- LayerNorm over RANK cols of qkv (cols NQ..NQ+511) --------------
__global__ void ln_kv(const u16* __restrict__ qkv, const float* __restrict__ gamma,
                      const float* __restrict__ beta, u16* __restrict__ kv_c) {
    int row = blockIdx.x, tid = threadIdx.x;
    size_t base = (size_t)row * NQKV + NQ;
    float x0 = b2f(qkv[base + tid]), x1 = b2f(qkv[base + 256 + tid]);
    float s = x0 + x1, q2 = x0 * x0 + x1 * x1;
    for (int o = 32; o > 0; o >>= 1) { s += __shfl_xor(s, o); q2 += __shfl_xor(q2, o); }
    __shared__ float sh[8];
    int lane = tid & 63, w = tid >> 6;
    if (lane == 0) { sh[w] = s; sh[4 + w] = q2; }
    __syncthreads();
    float S = sh[0] + sh[1] + sh[2] + sh[3];
    float Q2 = sh[4] + sh[5] + sh[6] + sh[7];
    float mu = S * (1.f / 512.f);
    float var = Q2 * (1.f / 512.f) - mu * mu;
    float rs = rsqrtf(var + 1e-5f);
    kv_c[(size_t)row * RANK + tid] =
        f2b((x0 - mu) * rs * gamma[tid] + beta[tid]);
    kv_c[(size_t)row * RANK + 256 + tid] =
        f2b((x1 - mu) * rs * gamma[256 + tid] + beta[256 + tid]);
}

// ---------------- assemble K in SWIZZLED MFMA-FRAGMENT order -----------------------
// Kf layout: [b][h][kt=32][kk=6][r=64][c=32] (u16) with the round-3 LDS swizzle
// baked in: u16 chunk offset = (c8 ^ ((r>>1 & 3)*8)). attn stages each 12288-u16
// tile to LDS with a LINEAR global_load_lds copy, so the LDS image is already
// the conflict-free-swizzled layout (both-sides rule satisfied by construction).
__global__ void k_assemble(const u16* __restrict__ kvb, const u16* __restrict__ qkv,
                           const float* __restrict__ freqs, u16* __restrict__ Kf) {
    int token = blockIdx.x;
    int b = token >> 11;              // SEQ = 2048
    int s = token & (SEQ - 1);
    int tid = threadIdx.x;
    __shared__ u16 roped[64];
    if (tid < 32) {
        int p = tid;
        float th = freqs[s * 32 + p];
        float c = __cosf(th), sn = __sinf(th);
        float x1 = b2f(qkv[(size_t)token * NQKV + NQ + RANK + 2 * p]);
        float x2 = b2f(qkv[(size_t)token * NQKV + NQ + RANK + 2 * p + 1]);
        roped[2 * p]     = f2b(x1 * c - x2 * sn);
        roped[2 * p + 1] = f2b(x1 * sn + x2 * c);
    }
    __syncthreads();
    int kt = s >> 6, r = s & 63;
    int swr = ((r >> 1) & 3) * 8;     // u16-index XOR (16B-chunk swizzle)
    {   // k_nope: 16 heads x 16 chunks of 8 u16; d = c8 in [0,128): kk = c8>>5
        int hh = tid >> 4, c8 = (tid & 15) * 8;
        size_t dst = ((size_t)(b * NH + hh) * 32 + kt) * 12288
                   + (size_t)(c8 >> 5) * 2048 + r * 32 + ((c8 & 31) ^ swr);
        *(u32x4*)&Kf[dst] = *(const u32x4*)&kvb[(size_t)token * NKVB + hh * 256 + c8];
    }
    if (tid < 128) {  // rope broadcast: d = 128 + c8 -> kk = 4 + (c8>>5)
        int hh = tid >> 3, c8 = (tid & 7) * 8;
        size_t dst = ((size_t)(b * NH + hh) * 32 + kt) * 12288
                   + (size_t)(4 + (c8 >> 5)) * 2048 + r * 32 + ((c8 & 31) ^ swr);
        *(u32x4*)&Kf[dst] = *(u32x4*)&roped[c8];
    }
}

// ---------------- V transpose into MFMA-FRAGMENT order ----------------------------
// Vt layout: [b][h][st=32][kk=2][dr=128][c=32] (u16), element = V[s=st*64+kk*32+c][dr]
// (read direct from global in attn -> no swizzle needed)
__global__ void v_transpose(const u16* __restrict__ kvb, u16* __restrict__ Vt) {
    __shared__ unsigned int t32[64 * 65];
    int bx = blockIdx.x;              // s-tile (64 rows)
    int st = bx * 64, dt = blockIdx.y * 64;
    int b = blockIdx.z >> 4, h = blockIdx.z & 15;
    int tid = threadIdx.x;
    for (int i = 0; i < 2; i++) {
        int u = tid + i * 256;
        int sl = u >> 3, c8 = (u & 7) * 8;
        u32x4 v = *(const u32x4*)&kvb[((size_t)(b * SEQ + st + sl) * NH + h) * 256 + DN + dt + c8];
        for (int j = 0; j < 4; j++) {
            t32[(c8 + 2 * j) * 65 + sl]     = v[j] & 0xffffu;
            t32[(c8 + 2 * j + 1) * 65 + sl] = v[j] >> 16;
        }
    }
    __syncthreads();
    for (int i = 0; i < 2; i++) {
        int u = tid + i * 256;
        int dl = u >> 3, s8 = (u & 7) * 8;     // within-tile s offset, multiple of 8
        unsigned int w[8];
        for (int j = 0; j < 8; j++) w[j] = t32[dl * 65 + s8 + j];
        u32x4 pk;
        for (int j = 0; j < 4; j++) pk[j] = (w[2 * j] & 0xffffu) | (w[2 * j + 1] << 16);
        size_t dst = ((size_t)(b * NH + h) * 32 + bx) * 8192
                   + (size_t)(s8 >> 5) * 4096 + (size_t)(dt + dl) * 32 + (s8 & 31);
        *(u32x4*)&Vt[dst] = pk;
    }
}

// ---------------- flash attention v5: K via gload_lds DMA, V direct, Q asm-pinned --
// LDS = K tile 24KB (single-buffered, pre-swizzled image via linear DMA) +
// P dbuf 2x8KB (PSTR=64, XOR swizzle (ln&7)<<4) = 40KB exactly -> 4 blocks/CU.
// Q fragments loaded once via volatile asm global_load_dwordx4 (cannot be
// rematerialized -> no per-iter Q reloads, the round-4 regression cause).
// 2 barriers/iter: [vmcnt(0); bar; QK(LDS); P-store; bar; issue stage(t+1) DMA; PV].
// Stage DMA flies under PV + softmax; drained only at next loop top.
#define KC    64
#define QTILE 64
#define NIT  (SEQ / KC)
__global__ __launch_bounds__(256, 4) void attn_kernel(const u16* __restrict__ Q,
                                                      const u16* __restrict__ Kf,
                                                      const u16* __restrict__ Vt,
                                                      u16* __restrict__ O) {
    __shared__ u16 Ks[6 * 64 * 32];      // 24 KB swizzled K tile
    __shared__ u16 Ps[2][QTILE * 64];    // 16 KB double-buffered P (XOR-swizzled)
    int tid = threadIdx.x, lane = tid & 63, w = tid >> 6;
    int w1 = w & 1;    // q 32-half
    int w2 = w >> 1;   // kv 32-half (QK) / d 64-half (PV)
    int g = lane >> 4, ln = lane & 15;
    // XCD-bijective swizzle (1024 % 8 == 0)
    int bid = blockIdx.x;
    int swz = ((bid & 7) << 7) | (bid >> 3);
    int qt = swz & 31, h = (swz >> 5) & 15, b = swz >> 9;

    size_t qbase = ((size_t)(b * SEQ + qt * QTILE)) * NQKV + h * DQK;
    const u16* Kh = Kf + (size_t)(b * NH + h) * (32 * 12288);
    const u16* Vh = Vt + (size_t)(b * NH + h) * (32 * 8192);

    // Q fragments -> pinned registers (opaque asm loads, no remat possible)
    u32x4 qreg[2][6];
#pragma unroll
    for (int ni = 0; ni < 2; ni++)
#pragma unroll
        for (int kk = 0; kk < 6; kk++) {
            const u16* qp = &Q[qbase + (size_t)(w1 * 32 + ni * 16 + ln) * NQKV + kk * 32 + g * 8];
            asm volatile("global_load_dwordx4 %0, %1, off"
                         : "=v"(qreg[ni][kk]) : "v"(qp));
        }
    // stage K tile 0 (linear DMA copy of pre-swizzled global image)
#pragma unroll
    for (int i = 0; i < 6; i++)
        gld_lds16(&Kh[i * 2048 + tid * 8], &Ks[i * 2048 + tid * 8]);

    // hoisted offsets
    int kRd0 = (w2 * 32 + ln) * 64 + ((g * 16) ^ (((ln >> 1) & 3) << 4));  // bytes
    int kRd1 = kRd0 + 16 * 64;
    int vrow = w2 * 2048 + ln * 32 + g * 8;   // u16, + kk*4096 + ni*512
    int pswz = (ln & 7) << 4;

    f32x4 oacc[2][4] = {};
    float lpriv[2] = {0.f, 0.f};

    for (int kt = 0; kt < NIT; kt++) {
        asm volatile("s_waitcnt vmcnt(0)" ::: "memory");
        __builtin_amdgcn_sched_barrier(0);
        __syncthreads();                   // K(kt) visible to all waves
        // S^T[kv][q] = K . Q^T from LDS (conflict-free swizzled reads)
        const char* KsB = (const char*)Ks;
        f32x4 sacc[2][2] = {};
#pragma unroll
        for (int kk = 0; kk < 6; kk++) {
            bf16x8 af0 = lds_frag((const u16*)(KsB + kk * 4096 + kRd0));
            bf16x8 af1 = lds_frag((const u16*)(KsB + kk * 4096 + kRd1));
            bf16x8 q0 = to_frag(qreg[0][kk]), q1 = to_frag(qreg[1][kk]);
            sacc[0][0] = mfma16(af0, q0, sacc[0][0]);
            sacc[0][1] = mfma16(af0, q1, sacc[0][1]);
            sacc[1][0] = mfma16(af1, q0, sacc[1][0]);
            sacc[1][1] = mfma16(af1, q1, sacc[1][1]);
        }
        // exp2 + private row-sum + packed b64 P store into Ps[kt&1] (swizzled)
        char* Pb = (char*)Ps[kt & 1];
#pragma unroll
        for (int mi = 0; mi < 2; mi++)
#pragma unroll
            for (int ni = 0; ni < 2; ni++) {
                float p0 = exp2f(sacc[mi][ni][0] * SCALE_LOG2E);
                float p1 = exp2f(sacc[mi][ni][1] * SCALE_LOG2E);
                float p2 = exp2f(sacc[mi][ni][2] * SCALE_LOG2E);
                float p3 = exp2f(sacc[mi][ni][3] * SCALE_LOG2E);
                lpriv[ni] += (p0 + p1) + (p2 + p3);
                unsigned int c0, c1;
                asm("v_cvt_pk_bf16_f32 %0, %1, %2" : "=v"(c0) : "v"(p0), "v"(p1));
                asm("v_cvt_pk_bf16_f32 %0, %1, %2" : "=v"(c1) : "v"(p2), "v"(p3));
                uint2 pk; pk.x = c0; pk.y = c1;
                int pwB = (w1 * 32 + ni * 16 + ln) * 128
                        + ((w2 * 64 + mi * 32 + g * 8) ^ pswz);
                *(uint2*)(Pb + pwB) = pk;
            }
        __syncthreads();                   // P(kt) ready; K(kt) reads done
        // issue next K-tile DMA (overlaps PV; drained at next loop top)
        if (kt + 1 < NIT) {
            const u16* kT = Kh + (size_t)(kt + 1) * 12288;
#pragma unroll
            for (int i = 0; i < 6; i++)
                gld_lds16(&kT[i * 2048 + tid * 8], &Ks[i * 2048 + tid * 8]);
        }
        // O[q][d] += P . V   (P from LDS, V direct from L2 in fragment order)
        const u16* vT = Vh + (size_t)kt * 8192;
#pragma unroll
        for (int kk = 0; kk < 2; kk++) {
            bf16x8 pa[2], vb[4];
#pragma unroll
            for (int mi = 0; mi < 2; mi++)
                pa[mi] = lds_frag((const u16*)(Pb + (w1 * 32 + mi * 16 + ln) * 128
                                               + ((kk * 64 + g * 16) ^ pswz)));
#pragma unroll
            for (int ni = 0; ni < 4; ni++)
                vb[ni] = to_frag(*(const u32x4*)&vT[kk * 4096 + ni * 512 + vrow]);
#pragma unroll
            for (int mi = 0; mi < 2; mi++)
#pragma unroll
                for (int ni = 0; ni < 4; ni++)
                    oacc[mi][ni] = mfma16(pa[mi], vb[ni], oacc[mi][ni]);
        }
    }

    // final lsum reduction (overlay on Ps[0]: last PV read Ps[1], Ps[0] idle)
    float* lsumF = (float*)Ps[0];
    for (int ni = 0; ni < 2; ni++) {
        float v = lpriv[ni];
        v += __shfl_xor(v, 16);
        v += __shfl_xor(v, 32);
        if (g == 0) lsumF[w2 * 64 + w1 * 32 + ni * 16 + ln] = v;
    }
    __syncthreads();
    for (int mi = 0; mi < 2; mi++)
        for (int ni = 0; ni < 4; ni++) {
            int d = w2 * 64 + ni * 16 + ln;
            for (int r = 0; r < 4; r++) {
                int row = w1 * 32 + mi * 16 + g * 4 + r;
                float l = lsumF[row] + lsumF[64 + row];
                O[((size_t)(b * SEQ + qt * QTILE + row) * NH + h) * DV + d] =
                    f2b(oacc[mi][ni][r] / l);
            }
        }
}

// ---------------- launcher ----------------
extern "C" void kernel_launch(void* const* d_in, const int* in_sizes, int n_in,
                              void* d_out, int out_size, void* d_ws, size_t ws_size,
                              hipStream_t stream) {
    const float* hs_f  = (const float*)d_in[0];
    const float* freqs = (const float*)d_in[1];
    const float* Wq    = (const float*)d_in[2];
    const float* Wkva  = (const float*)d_in[3];
    const float* gamma = (const float*)d_in[4];
    const float* beta  = (const float*)d_in[5];
    const float* Wkvb  = (const float*)d_in[6];
    const float* Wout  = (const float*)d_in[7];
    float* outp = (float*)d_out;

    char* ws = (char*)d_ws;
    size_t off = 0;
    auto alloc = [&](size_t elems) -> u16* {
        u16* p = (u16*)(ws + off);
        off += ((elems * 2 + 255) / 256) * 256;
        return p;
    };
    u16* hs     = alloc((size_t)NTOK * HID);
    u16* WqkvT  = alloc((size_t)NQKV * HID);     // rows 0..3071 Wq^T, 3072..3711 Wkva^T (padded)
    u16* WkvbT  = alloc((size_t)NKVB * RANK);
    u16* WoutT  = alloc((size_t)HID * HID);
    u16* qkv    = alloc((size_t)NTOK * NQKV);    // q | kv_a output
    u16* kv_c   = alloc((size_t)NTOK * RANK);
    u16* kvb    = alloc((size_t)NTOK * NKVB);
    u16* Kf     = alloc((size_t)NTOK * NQ);      // swizzled fragment-order K
    u16* Vt     = alloc((size_t)BATCH * NH * DV * SEQ);  // fragment-order V^T
    u16* attn   = alloc((size_t)NTOK * NH * DV);
    (void)ws_size; (void)in_sizes; (void)n_in; (void)out_size;

    // 1. fused prep: cast + all weight transposes
    prep_kernel<<<8192 + 1536 + 320 + 512 + 1024, 256, 0, stream>>>(
        hs_f, hs, Wq, Wkva, Wkvb, Wout, WqkvT, WkvbT, WoutT);

    // 2. fused q + kv_a GEMM: (4096 x 3712 x 2048)
    gemm_bt<<<dim3(NQKV / 128, NTOK / 128), 256, 0, stream>>>(hs, WqkvT, qkv, HID, HID, HID, NQKV);

    // 3. RoPE on q (in place)
    rope_q<<<NTOK, 256, 0, stream>>>(qkv, freqs);

    // 4. layernorm
    ln_kv<<<NTOK, 256, 0, stream>>>(qkv, gamma, beta, kv_c);

    // 5. kvb = kv_c @ Wkv_b (4096 x 4096 x 512)
    gemm_bt<<<dim3(NKVB / 128, NTOK / 128), 256, 0, stream>>>(kv_c, WkvbT, kvb, RANK, RANK, RANK, NKVB);

    // 6. K assembly (swizzled fragment-order)
    k_assemble<<<NTOK, 256, 0, stream>>>(kvb, qkv, freqs, Kf);

    // 7. V transpose (fragment-order)
    v_transpose<<<dim3(SEQ / 64, DV / 64, BATCH * NH), 256, 0, stream>>>(kvb, Vt);

    // 8. attention (v5: K DMA-staged, V direct, Q pinned, 2 barriers/iter)
    attn_kernel<<<1024, 256, 0, stream>>>(qkv, Kf, Vt, attn);

    // 9. out = attn @ Wout (4096 x 2048 x 2048)
    gemm_bt<<<dim3(HID / 128, NTOK / 128), 256, 0, stream>>>(attn, WoutT, outp, HID, HID, HID, HID);
}

// Round 6
// 421.881 us; speedup vs baseline: 1.2003x; 1.1374x over previous
//
#include <hip/hip_runtime.h>

// ---------------- constants ----------------
#define BATCH 2
#define SEQ   2048
#define HID   2048
#define NH    16
#define DN    128
#define DR    64
#define DV    128
#define RANK  512
#define DQK   192            // DN + DR
#define NQ    (NH*DQK)       // 3072
#define NQKV  3840           // NQ + 768 pad (= 15*256 for 256-tile GEMM)
#define NKVB  (NH*(DN+DV))   // 4096
#define NTOK  (BATCH*SEQ)    // 4096
#define SCALE_F 0.07216878364870323f  // 192^-0.5
#define SCALE_LOG2E 0.10411754831420211f  // SCALE_F * log2(e)

typedef __bf16 bf16x8 __attribute__((ext_vector_type(8)));
typedef float  f32x4  __attribute__((ext_vector_type(4)));
typedef unsigned int u32x4 __attribute__((ext_vector_type(4)));
typedef unsigned short u16;
typedef unsigned short u16x4 __attribute__((ext_vector_type(4)));

__device__ __forceinline__ float b2f(u16 h) {
    unsigned int u = ((unsigned int)h) << 16;
    float f; __builtin_memcpy(&f, &u, 4); return f;
}
__device__ __forceinline__ u16 f2b(float f) {
    unsigned int x; __builtin_memcpy(&x, &f, 4);
    unsigned int r = x + 0x7fffu + ((x >> 16) & 1u);
    return (u16)(r >> 16);
}
__device__ __forceinline__ bf16x8 lds_frag(const u16* p) {
    u32x4 v = *(const u32x4*)p;
    return __builtin_bit_cast(bf16x8, v);
}
__device__ __forceinline__ bf16x8 to_frag(u32x4 v) {
    return __builtin_bit_cast(bf16x8, v);
}
__device__ __forceinline__ f32x4 mfma16(bf16x8 a, bf16x8 b, f32x4 c) {
    return __builtin_amdgcn_mfma_f32_16x16x32_bf16(a, b, c, 0, 0, 0);
}
__device__ __forceinline__ void store_out(u16* p, float v) { *p = f2b(v); }
__device__ __forceinline__ void store_out(float* p, float v) { *p = v; }
__device__ __forceinline__ void gld_lds16(const u16* g, u16* l) {
    __builtin_amdgcn_global_load_lds(
        (const __attribute__((address_space(1))) unsigned int*)g,
        (__attribute__((address_space(3))) unsigned int*)l, 16, 0, 0);
}

// ---------------- fused prep: hs cast + 4 weight transposes, one launch ----------
__global__ __launch_bounds__(256) void prep_kernel(
        const float* __restrict__ hs_f, u16* __restrict__ hs,
        const float* __restrict__ Wq, const float* __restrict__ Wkva,
        const float* __restrict__ Wkvb, const float* __restrict__ Wout,
        u16* __restrict__ WqkvT, u16* __restrict__ WkvbT, u16* __restrict__ WoutT) {
    int tid = threadIdx.x;
    int bid = blockIdx.x;
    if (bid < 8192) {            // cast: 8192*256 f32x4 = NTOK*HID elems
        int i = bid * 256 + tid;
        f32x4 v = *(const f32x4*)(hs_f + (size_t)i * 4);
        u16 o[4];
        for (int k = 0; k < 4; k++) o[k] = f2b(v[k]);
        *(unsigned long long*)(hs + (size_t)i * 4) = *(unsigned long long*)o;
        return;
    }
    bid -= 8192;
    const float* in; u16* out; int R, C, tilesC;
    if (bid < 1536)      { in = Wq;   out = WqkvT;                       R = HID;  C = NQ;   tilesC = 48; }
    else if (bid < 1920) { bid -= 1536; in = Wkva; out = WqkvT + (size_t)NQ * HID; R = HID; C = 576; tilesC = 12; }  // 12 tiles -> fills+zeros rows 3072..3839
    else if (bid < 2432) { bid -= 1920; in = Wkvb; out = WkvbT;          R = RANK; C = NKVB; tilesC = 64; }
    else                 { bid -= 2432; in = Wout; out = WoutT;          R = HID;  C = HID;  tilesC = 32; }
    __shared__ unsigned int t32[64 * 65];
    int r0 = (bid / tilesC) * 64, c0 = (bid % tilesC) * 64;
    bool valid = (c0 < C);
    for (int i = 0; i < 4; i++) {
        int u = tid + i * 256;
        int rl = u >> 4, c4 = u & 15;
        f32x4 v = {0.f, 0.f, 0.f, 0.f};
        if (valid) v = *(const f32x4*)&in[(size_t)(r0 + rl) * C + c0 + c4 * 4];
        for (int j = 0; j < 4; j++)
            t32[(c4 * 4 + j) * 65 + rl] = f2b(v[j]);
    }
    __syncthreads();
    for (int i = 0; i < 2; i++) {
        int u = tid + i * 256;
        int cl = u >> 3, r8 = (u & 7) * 8;
        unsigned int w[8];
        for (int j = 0; j < 8; j++) w[j] = t32[cl * 65 + r8 + j];
        u32x4 pk;
        for (int j = 0; j < 4; j++) pk[j] = (w[2 * j] & 0xffffu) | (w[2 * j + 1] << 16);
        *(u32x4*)&out[(size_t)(c0 + cl) * R + r0 + r8] = pk;
    }
}

// ---------------- generic bf16 GEMM: C[M,N] = A[M,K] * Bt[N,K]^T (m97 pattern) ----
template <typename OutT>
__global__ __launch_bounds__(256) void gemm_bt(const u16* __restrict__ A,
                                               const u16* __restrict__ Bt,
                                               OutT* __restrict__ C,
                                               int K, int lda, int ldb, int ldc) {
    __shared__ u16 As[128 * 32];
    __shared__ u16 Bs[128 * 32];
    int tid = threadIdx.x, lane = tid & 63, w = tid >> 6;
    int wm = (w >> 1) * 64, wn = (w & 1) * 64;
    int g = lane >> 4, ln = lane & 15;
    int m0 = blockIdx.y * 128, n0 = blockIdx.x * 128;
    f32x4 acc[4][4] = {};
    for (int k0 = 0; k0 < K; k0 += 32) {
        for (int i = 0; i < 2; i++) {
            int ch = tid + i * 256;
            int row = ch >> 2, o = ch & 3;
            gld_lds16(&A[(size_t)(m0 + row) * lda + k0 + o * 8], &As[row * 32 + o * 8]);
            gld_lds16(&Bt[(size_t)(n0 + row) * ldb + k0 + o * 8], &Bs[row * 32 + o * 8]);
        }
        __syncthreads();
        bf16x8 af[4], bf[4];
        for (int i = 0; i < 4; i++) af[i] = lds_frag(&As[(wm + i * 16 + ln) * 32 + g * 8]);
        for (int j = 0; j < 4; j++) bf[j] = lds_frag(&Bs[(wn + j * 16 + ln) * 32 + g * 8]);
        for (int i = 0; i < 4; i++)
            for (int j = 0; j < 4; j++)
                acc[i][j] = mfma16(af[i], bf[j], acc[i][j]);
        __syncthreads();
    }
    for (int i = 0; i < 4; i++)
        for (int j = 0; j < 4; j++)
            for (int r = 0; r < 4; r++) {
                int m = m0 + wm + i * 16 + g * 4 + r;
                int n = n0 + wn + j * 16 + ln;
                store_out(&C[(size_t)m * ldc + n], acc[i][j][r]);
            }
}

// ---------------- 256x256 / BK=64 / 8-wave dbuf GEMM (T2+T3-lite+T5) --------------
// C[M,N] = A[M,K] * Bt[N,K]^T. 512 thr = 8 waves (2M x 4N), per-wave out 128x64.
// LDS: 8 x 16KB half-tiles [dbuf][A/B][half(128 rows)], row = 64 u16 = 8 chunks of
// 16B. Swizzle: chunk' = chunk ^ (row&7); staged via PRE-SWIZZLED GLOBAL SOURCE +
// linear gld_lds dest (rule #21 by construction); reads XOR the same term ->
// 2 lanes/slot (free, m136). Per K-tile: 4 quadrant phases; stages for tile t+1
// issued at phases 0-1 (2 half-tiles each); publish ONCE per tile: per-wave
// s_waitcnt vmcnt(0) BEFORE the boundary raw s_barrier (~3 phases of cover).
// Raw __builtin s_barrier (no compiler vmcnt-drain). setprio(1) around MFMA.
template <typename OutT>
__global__ __launch_bounds__(512, 2) void gemm256(const u16* __restrict__ A,
                                                  const u16* __restrict__ Bt,
                                                  OutT* __restrict__ C,
                                                  int K, int lda, int ldb, int ldc) {
    __shared__ u16 lds[8][128 * 64];     // 128 KB
    int tid = threadIdx.x, lane = tid & 63, w = tid >> 6;
    int wm = w >> 2, wn = w & 3;
    int g = lane >> 4, ln = lane & 15;
    int m0 = blockIdx.y * 256, n0 = blockIdx.x * 256;

    // staging addressing: thread -> (row 0..63 per load, chunk), pre-swizzled src
    int srow = tid >> 3, schunk = tid & 7;
    int cs = schunk ^ (srow & 7);
    int sdst = tid * 8;                   // u16; +4096 for second 64-row load

    auto stage = [&](int p, int ht, int t) {   // ht: 0=A0,1=A1,2=B0,3=B1
        const u16* src = (ht < 2) ? A : Bt;
        int ld = (ht < 2) ? lda : ldb;
        int base = ((ht < 2) ? m0 : n0) + (ht & 1) * 128;
        u16* buf = lds[p * 4 + ht];
        int k0 = t << 6;
        gld_lds16(&src[(size_t)(base + srow) * ld + k0 + cs * 8], &buf[sdst]);
        gld_lds16(&src[(size_t)(base + 64 + srow) * ld + k0 + cs * 8], &buf[4096 + sdst]);
    };

    // fragment read offsets (u16): row term + swizzled chunk term
    int aR = ln * 64;
    int ck0 = ((g ^ (ln & 7)) << 3);          // kk=0: chunk g
    int ck1 = (((4 + g) ^ (ln & 7)) << 3);    // kk=1: chunk 4+g
    int bB = (wn & 1) * 4096;                  // B row offset within half

    f32x4 acc[8][4] = {};
    int NT = K >> 6;

    // prologue: stage tile 0, publish
    for (int ht = 0; ht < 4; ht++) stage(0, ht, 0);
    __builtin_amdgcn_sched_barrier(0);
    asm volatile("s_waitcnt vmcnt(0)" ::: "memory");
    __builtin_amdgcn_sched_barrier(0);
    __builtin_amdgcn_s_barrier();

    for (int t = 0; t < NT; t++) {
        const u16* Ab = lds[(t & 1) * 4 + wm];
        const u16* Bb = lds[(t & 1) * 4 + 2 + (wn >> 1)];
        int pn = (t & 1) ^ 1;
        bool pf = (t + 1 < NT);
        bf16x8 af[4][2], bf[4][2];

        // ---- phase 0: quadrant (Mhalf0, Nfrags0-1)
#pragma unroll
        for (int f = 0; f < 4; f++) {
            af[f][0] = lds_frag(&Ab[f * 1024 + aR + ck0]);
            af[f][1] = lds_frag(&Ab[f * 1024 + aR + ck1]);
        }
#pragma unroll
        for (int nf = 0; nf < 2; nf++) {
            bf[nf][0] = lds_frag(&Bb[bB + nf * 1024 + aR + ck0]);
            bf[nf][1] = lds_frag(&Bb[bB + nf * 1024 + aR + ck1]);
        }
        if (pf) { stage(pn, 0, t + 1); stage(pn, 1, t + 1); }
        __builtin_amdgcn_s_barrier();
        __builtin_amdgcn_s_setprio(1);
#pragma unroll
        for (int f = 0; f < 4; f++)
#pragma unroll
            for (int nf = 0; nf < 2; nf++) {
                acc[f][nf] = mfma16(af[f][0], bf[nf][0], acc[f][nf]);
                acc[f][nf] = mfma16(af[f][1], bf[nf][1], acc[f][nf]);
            }
        __builtin_amdgcn_s_setprio(0);

        // ---- phase 1: quadrant (Mhalf0, Nfrags2-3)
#pragma unroll
        for (int nf = 2; nf < 4; nf++) {
            bf[nf][0] = lds_frag(&Bb[bB + nf * 1024 + aR + ck0]);
            bf[nf][1] = lds_frag(&Bb[bB + nf * 1024 + aR + ck1]);
        }
        if (pf) { stage(pn, 2, t + 1); stage(pn, 3, t + 1); }
        __builtin_amdgcn_s_barrier();
        __builtin_amdgcn_s_setprio(1);
#pragma unroll
        for (int f = 0; f < 4; f++)
#pragma unroll
            for (int nf = 2; nf < 4; nf++) {
                acc[f][nf] = mfma16(af[f][0], bf[nf][0], acc[f][nf]);
                acc[f][nf] = mfma16(af[f][1], bf[nf][1], acc[f][nf]);
            }
        __builtin_amdgcn_s_setprio(0);

        // ---- phase 2: quadrant (Mhalf1, Nfrags0-1)
#pragma unroll
        for (int f = 0; f < 4; f++) {
            af[f][0] = lds_frag(&Ab[(f + 4) * 1024 + aR + ck0]);
            af[f][1] = lds_frag(&Ab[(f + 4) * 1024 + aR + ck1]);
        }
        __builtin_amdgcn_s_barrier();
        __builtin_amdgcn_s_setprio(1);
#pragma unroll
        for (int f = 0; f < 4; f++)
#pragma unroll
            for (int nf = 0; nf < 2; nf++) {
                acc[f + 4][nf] = mfma16(af[f][0], bf[nf][0], acc[f + 4][nf]);
                acc[f + 4][nf] = mfma16(af[f][1], bf[nf][1], acc[f + 4][nf]);
            }
        __builtin_amdgcn_s_setprio(0);

        // ---- phase 3: quadrant (Mhalf1, Nfrags2-3)
        __builtin_amdgcn_s_barrier();
        __builtin_amdgcn_s_setprio(1);
#pragma unroll
        for (int f = 0; f < 4; f++)
#pragma unroll
            for (int nf = 2; nf < 4; nf++) {
                acc[f + 4][nf] = mfma16(af[f][0], bf[nf][0], acc[f + 4][nf]);
                acc[f + 4][nf] = mfma16(af[f][1], bf[nf][1], acc[f + 4][nf]);
            }
        __builtin_amdgcn_s_setprio(0);

        // ---- tile boundary: publish dbuf pn (per-wave drain BEFORE barrier)
        if (pf) {
            __builtin_amdgcn_sched_barrier(0);
            asm volatile("s_waitcnt vmcnt(0)" ::: "memory");
            __builtin_amdgcn_sched_barrier(0);
            __builtin_amdgcn_s_barrier();
        }
    }

    // epilogue: C write
#pragma unroll
    for (int f = 0; f < 8; f++)
#pragma unroll
        for (int nf = 0; nf < 4; nf++)
#pragma unroll
            for (int r = 0; r < 4; r++) {
                int m = m0 + wm * 128 + f * 16 + g * 4 + r;
                int n = n0 + wn * 64 + nf * 16 + ln;
                store_out(&C[(size_t)m * ldc + n], acc[f][nf][r]);
            }
}

// ---------------- RoPE on q (in-place on qkv, last 64 of each head's 192) --------
__global__ void rope_q(u16* __restrict__ qkv, const float* __restrict__ freqs) {
    int token = blockIdx.x;
    int s = token & (SEQ - 1);
    int tid = threadIdx.x;
    for (int i = 0; i < 2; i++) {
        int idx = tid + i * 256;          // 512 pairs = 16 heads * 32
        int hh = idx >> 5, p = idx & 31;
        float th = freqs[s * 32 + p];
        float c = __cosf(th), sn = __sinf(th);
        size_t off = (size_t)token * NQKV + hh * DQK + DN + 2 * p;
        float x1 = b2f(qkv[off]), x2 = b2f(qkv[off + 1]);
        qkv[off]     = f2b(x1 * c - x2 * sn);
        qkv[off + 1] = f2b(x1 * sn + x2 * c);
    }
}

// ---------------- LayerNorm over RANK cols of qkv (cols NQ..NQ+511) --------------
__global__ void ln_kv(const u16* __restrict__ qkv, const float* __restrict__ gamma,
                      const float* __restrict__ beta, u16* __restrict__ kv_c) {
    int row = blockIdx.x, tid = threadIdx.x;
    size_t base = (size_t)row * NQKV + NQ;
    float x0 = b2f(qkv[base + tid]), x1 = b2f(qkv[base + 256 + tid]);
    float s = x0 + x1, q2 = x0 * x0 + x1 * x1;
    for (int o = 32; o > 0; o >>= 1) { s += __shfl_xor(s, o); q2 += __shfl_xor(q2, o); }
    __shared__ float sh[8];
    int lane = tid & 63, w = tid >> 6;
    if (lane == 0) { sh[w] = s; sh[4 + w] = q2; }
    __syncthreads();
    float S = sh[0] + sh[1] + sh[2] + sh[3];
    float Q2 = sh[4] + sh[5] + sh[6] + sh[7];
    float mu = S * (1.f / 512.f);
    float var = Q2 * (1.f / 512.f) - mu * mu;
    float rs = rsqrtf(var + 1e-5f);
    kv_c[(size_t)row * RANK + tid] =
        f2b((x0 - mu) * rs * gamma[tid] + beta[tid]);
    kv_c[(size_t)row * RANK + 256 + tid] =
        f2b((x1 - mu) * rs * gamma[256 + tid] + beta[256 + tid]);
}

// ---------------- assemble K in SWIZZLED MFMA-FRAGMENT order -----------------------
// Kf layout: [b][h][kt=32][kk=6][r=64][c=32] (u16) with chunk swizzle
// (c8 ^ ((r>>1 & 3)*8)) baked in; attn stages linearly via gld_lds.
__global__ void k_assemble(const u16* __restrict__ kvb, const u16* __restrict__ qkv,
                           const float* __restrict__ freqs, u16* __restrict__ Kf) {
    int token = blockIdx.x;
    int b = token >> 11;              // SEQ = 2048
    int s = token & (SEQ - 1);
    int tid = threadIdx.x;
    __shared__ u16 roped[64];
    if (tid < 32) {
        int p = tid;
        float th = freqs[s * 32 + p];
        float c = __cosf(th), sn = __sinf(th);
        float x1 = b2f(qkv[(size_t)token * NQKV + NQ + RANK + 2 * p]);
        float x2 = b2f(qkv[(size_t)token * NQKV + NQ + RANK + 2 * p + 1]);
        roped[2 * p]     = f2b(x1 * c - x2 * sn);
        roped[2 * p + 1] = f2b(x1 * sn + x2 * c);
    }
    __syncthreads();
    int kt = s >> 6, r = s & 63;
    int swr = ((r >> 1) & 3) * 8;     // u16-index XOR (16B-chunk swizzle)
    {   // k_nope: 16 heads x 16 chunks of 8 u16; d = c8 in [0,128): kk = c8>>5
        int hh = tid >> 4, c8 = (tid & 15) * 8;
        size_t dst = ((size_t)(b * NH + hh) * 32 + kt) * 12288
                   + (size_t)(c8 >> 5) * 2048 + r * 32 + ((c8 & 31) ^ swr);
        *(u32x4*)&Kf[dst] = *(const u32x4*)&kvb[(size_t)token * NKVB + hh * 256 + c8];
    }
    if (tid < 128) {  // rope broadcast: d = 128 + c8 -> kk = 4 + (c8>>5)
        int hh = tid >> 3, c8 = (tid & 7) * 8;
        size_t dst = ((size_t)(b * NH + hh) * 32 + kt) * 12288
                   + (size_t)(4 + (c8 >> 5)) * 2048 + r * 32 + ((c8 & 31) ^ swr);
        *(u32x4*)&Kf[dst] = *(u32x4*)&roped[c8];
    }
}

// ---------------- V transpose into MFMA-FRAGMENT order ----------------------------
// Vt layout: [b][h][st=32][kk=2][dr=128][c=32] (u16), element = V[s=st*64+kk*32+c][dr]
__global__ void v_transpose(const u16* __restrict__ kvb, u16* __restrict__ Vt) {
    __shared__ unsigned int t32[64 * 65];
    int bx = blockIdx.x;              // s-tile (64 rows)
    int st = bx * 64, dt = blockIdx.y * 64;
    int b = blockIdx.z >> 4, h = blockIdx.z & 15;
    int tid = threadIdx.x;
    for (int i = 0; i < 2; i++) {
        int u = tid + i * 256;
        int sl = u >> 3, c8 = (u & 7) * 8;
        u32x4 v = *(const u32x4*)&kvb[((size_t)(b * SEQ + st + sl) * NH + h) * 256 + DN + dt + c8];
        for (int j = 0; j < 4; j++) {
            t32[(c8 + 2 * j) * 65 + sl]     = v[j] & 0xffffu;
            t32[(c8 + 2 * j + 1) * 65 + sl] = v[j] >> 16;
        }
    }
    __syncthreads();
    for (int i = 0; i < 2; i++) {
        int u = tid + i * 256;
        int dl = u >> 3, s8 = (u & 7) * 8;     // within-tile s offset, multiple of 8
        unsigned int w[8];
        for (int j = 0; j < 8; j++) w[j] = t32[dl * 65 + s8 + j];
        u32x4 pk;
        for (int j = 0; j < 4; j++) pk[j] = (w[2 * j] & 0xffffu) | (w[2 * j + 1] << 16);
        size_t dst = ((size_t)(b * NH + h) * 32 + bx) * 8192
                   + (size_t)(s8 >> 5) * 4096 + (size_t)(dt + dl) * 32 + (s8 & 31);
        *(u32x4*)&Vt[dst] = pk;
    }
}

// ---------------- flash attention v5 (unchanged from round 5, passing) ------------
#define KC    64
#define QTILE 64
#define NIT  (SEQ / KC)
__global__ __launch_bounds__(256, 4) void attn_kernel(const u16* __restrict__ Q,
                                                      const u16* __restrict__ Kf,
                                                      const u16* __restrict__ Vt,
                                                      u16* __restrict__ O) {
    __shared__ u16 Ks[6 * 64 * 32];      // 24 KB swizzled K tile
    __shared__ u16 Ps[2][QTILE * 64];    // 16 KB double-buffered P (XOR-swizzled)
    int tid = threadIdx.x, lane = tid & 63, w = tid >> 6;
    int w1 = w & 1;    // q 32-half
    int w2 = w >> 1;   // kv 32-half (QK) / d 64-half (PV)
    int g = lane >> 4, ln = lane & 15;
    int bid = blockIdx.x;
    int swz = ((bid & 7) << 7) | (bid >> 3);
    int qt = swz & 31, h = (swz >> 5) & 15, b = swz >> 9;

    size_t qbase = ((size_t)(b * SEQ + qt * QTILE)) * NQKV + h * DQK;
    const u16* Kh = Kf + (size_t)(b * NH + h) * (32 * 12288);
    const u16* Vh = Vt + (size_t)(b * NH + h) * (32 * 8192);

    // Q fragments -> pinned registers (opaque asm loads, no remat possible)
    u32x4 qreg[2][6];
#pragma unroll
    for (int ni = 0; ni < 2; ni++)
#pragma unroll
        for (int kk = 0; kk < 6; kk++) {
            const u16* qp = &Q[qbase + (size_t)(w1 * 32 + ni * 16 + ln) * NQKV + kk * 32 + g * 8];
            asm volatile("global_load_dwordx4 %0, %1, off"
                         : "=v"(qreg[ni][kk]) : "v"(qp));
        }
    // stage K tile 0 (linear DMA copy of pre-swizzled global image)
#pragma unroll
    for (int i = 0; i < 6; i++)
        gld_lds16(&Kh[i * 2048 + tid * 8], &Ks[i * 2048 + tid * 8]);

    int kRd0 = (w2 * 32 + ln) * 64 + ((g * 16) ^ (((ln >> 1) & 3) << 4));  // bytes
    int kRd1 = kRd0 + 16 * 64;
    int vrow = w2 * 2048 + ln * 32 + g * 8;   // u16, + kk*4096 + ni*512
    int pswz = (ln & 7) << 4;

    f32x4 oacc[2][4] = {};
    float lpriv[2] = {0.f, 0.f};

    for (int kt = 0; kt < NIT; kt++) {
        asm volatile("s_waitcnt vmcnt(0)" ::: "memory");
        __builtin_amdgcn_sched_barrier(0);
        __syncthreads();                   // K(kt) visible to all waves
        const char* KsB = (const char*)Ks;
        f32x4 sacc[2][2] = {};
#pragma unroll
        for (int kk = 0; kk < 6; kk++) {
            bf16x8 af0 = lds_frag((const u16*)(KsB + kk * 4096 + kRd0));
            bf16x8 af1 = lds_frag((const u16*)(KsB + kk * 4096 + kRd1));
            bf16x8 q0 = to_frag(qreg[0][kk]), q1 = to_frag(qreg[1][kk]);
            sacc[0][0] = mfma16(af0, q0, sacc[0][0]);
            sacc[0][1] = mfma16(af0, q1, sacc[0][1]);
            sacc[1][0] = mfma16(af1, q0, sacc[1][0]);
            sacc[1][1] = mfma16(af1, q1, sacc[1][1]);
        }
        char* Pb = (char*)Ps[kt & 1];
#pragma unroll
        for (int mi = 0; mi < 2; mi++)
#pragma unroll
            for (int ni = 0; ni < 2; ni++) {
                float p0 = exp2f(sacc[mi][ni][0] * SCALE_LOG2E);
                float p1 = exp2f(sacc[mi][ni][1] * SCALE_LOG2E);
                float p2 = exp2f(sacc[mi][ni][2] * SCALE_LOG2E);
                float p3 = exp2f(sacc[mi][ni][3] * SCALE_LOG2E);
                lpriv[ni] += (p0 + p1) + (p2 + p3);
                unsigned int c0, c1;
                asm("v_cvt_pk_bf16_f32 %0, %1, %2" : "=v"(c0) : "v"(p0), "v"(p1));
                asm("v_cvt_pk_bf16_f32 %0, %1, %2" : "=v"(c1) : "v"(p2), "v"(p3));
                uint2 pk; pk.x = c0; pk.y = c1;
                int pwB = (w1 * 32 + ni * 16 + ln) * 128
                        + ((w2 * 64 + mi * 32 + g * 8) ^ pswz);
                *(uint2*)(Pb + pwB) = pk;
            }
        __syncthreads();                   // P(kt) ready; K(kt) reads done
        if (kt + 1 < NIT) {
            const u16* kT = Kh + (size_t)(kt + 1) * 12288;
#pragma unroll
            for (int i = 0; i < 6; i++)
                gld_lds16(&kT[i * 2048 + tid * 8], &Ks[i * 2048 + tid * 8]);
        }
        const u16* vT = Vh + (size_t)kt * 8192;
#pragma unroll
        for (int kk = 0; kk < 2; kk++) {
            bf16x8 pa[2], vb[4];
#pragma unroll
            for (int mi = 0; mi < 2; mi++)
                pa[mi] = lds_frag((const u16*)(Pb + (w1 * 32 + mi * 16 + ln) * 128
                                               + ((kk * 64 + g * 16) ^ pswz)));
#pragma unroll
            for (int ni = 0; ni < 4; ni++)
                vb[ni] = to_frag(*(const u32x4*)&vT[kk * 4096 + ni * 512 + vrow]);
#pragma unroll
            for (int mi = 0; mi < 2; mi++)
#pragma unroll
                for (int ni = 0; ni < 4; ni++)
                    oacc[mi][ni] = mfma16(pa[mi], vb[ni], oacc[mi][ni]);
        }
    }

    float* lsumF = (float*)Ps[0];
    for (int ni = 0; ni < 2; ni++) {
        float v = lpriv[ni];
        v += __shfl_xor(v, 16);
        v += __shfl_xor(v, 32);
        if (g == 0) lsumF[w2 * 64 + w1 * 32 + ni * 16 + ln] = v;
    }
    __syncthreads();
    for (int mi = 0; mi < 2; mi++)
        for (int ni = 0; ni < 4; ni++) {
            int d = w2 * 64 + ni * 16 + ln;
            for (int r = 0; r < 4; r++) {
                int row = w1 * 32 + mi * 16 + g * 4 + r;
                float l = lsumF[row] + lsumF[64 + row];
                O[((size_t)(b * SEQ + qt * QTILE + row) * NH + h) * DV + d] =
                    f2b(oacc[mi][ni][r] / l);
            }
        }
}

// ---------------- launcher ----------------
extern "C" void kernel_launch(void* const* d_in, const int* in_sizes, int n_in,
                              void* d_out, int out_size, void* d_ws, size_t ws_size,
                              hipStream_t stream) {
    const float* hs_f  = (const float*)d_in[0];
    const float* freqs = (const float*)d_in[1];
    const float* Wq    = (const float*)d_in[2];
    const float* Wkva  = (const float*)d_in[3];
    const float* gamma = (const float*)d_in[4];
    const float* beta  = (const float*)d_in[5];
    const float* Wkvb  = (const float*)d_in[6];
    const float* Wout  = (const float*)d_in[7];
    float* outp = (float*)d_out;

    char* ws = (char*)d_ws;
    size_t off = 0;
    auto alloc = [&](size_t elems) -> u16* {
        u16* p = (u16*)(ws + off);
        off += ((elems * 2 + 255) / 256) * 256;
        return p;
    };
    u16* hs     = alloc((size_t)NTOK * HID);
    u16* WqkvT  = alloc((size_t)NQKV * HID);     // rows 0..3071 Wq^T, 3072..3839 Wkva^T (zero-padded)
    u16* WkvbT  = alloc((size_t)NKVB * RANK);
    u16* WoutT  = alloc((size_t)HID * HID);
    u16* qkv    = alloc((size_t)NTOK * NQKV);    // q | kv_a output
    u16* kv_c   = alloc((size_t)NTOK * RANK);
    u16* kvb    = alloc((size_t)NTOK * NKVB);
    u16* Kf     = alloc((size_t)NTOK * NQ);      // swizzled fragment-order K
    u16* Vt     = alloc((size_t)BATCH * NH * DV * SEQ);  // fragment-order V^T
    u16* attn   = alloc((size_t)NTOK * NH * DV);
    (void)ws_size; (void)in_sizes; (void)n_in; (void)out_size;

    // 1. fused prep: cast + all weight transposes (Wkva segment now 12 col-tiles)
    prep_kernel<<<8192 + 1536 + 384 + 512 + 1024, 256, 0, stream>>>(
        hs_f, hs, Wq, Wkva, Wkvb, Wout, WqkvT, WkvbT, WoutT);

    // 2. fused q + kv_a GEMM: (4096 x 3840 x 2048) on 256^2 8-wave kernel
    gemm256<<<dim3(NQKV / 256, NTOK / 256), 512, 0, stream>>>(hs, WqkvT, qkv, HID, HID, HID, NQKV);

    // 3. RoPE on q (in place)
    rope_q<<<NTOK, 256, 0, stream>>>(qkv, freqs);

    // 4. layernorm
    ln_kv<<<NTOK, 256, 0, stream>>>(qkv, gamma, beta, kv_c);

    // 5. kvb = kv_c @ Wkv_b (4096 x 4096 x 512) on 256^2 kernel
    gemm256<<<dim3(NKVB / 256, NTOK / 256), 512, 0, stream>>>(kv_c, WkvbT, kvb, RANK, RANK, RANK, NKVB);

    // 6. K assembly (swizzled fragment-order)
    k_assemble<<<NTOK, 256, 0, stream>>>(kvb, qkv, freqs, Kf);

    // 7. V transpose (fragment-order)
    v_transpose<<<dim3(SEQ / 64, DV / 64, BATCH * NH), 256, 0, stream>>>(kvb, Vt);

    // 8. attention (v5, unchanged)
    attn_kernel<<<1024, 256, 0, stream>>>(qkv, Kf, Vt, attn);

    // 9. out = attn @ Wout (4096 x 2048 x 2048) stays on 128^2 (N=2048 -> only 128
    //    blocks at 256^2 = half the CUs idle)
    gemm_bt<<<dim3(HID / 128, NTOK / 128), 256, 0, stream>>>(attn, WoutT, outp, HID, HID, HID, HID);
}

// Round 7
// 419.985 us; speedup vs baseline: 1.2058x; 1.0045x over previous
//
#include <hip/hip_runtime.h>

// ---------------- constants ----------------
#define BATCH 2
#define SEQ   2048
#define HID   2048
#define NH    16
#define DN    128
#define DR    64
#define DV    128
#define RANK  512
#define DQK   192            // DN + DR
#define NQ    (NH*DQK)       // 3072
#define NQKV  3840           // NQ + 768 pad (= 15*256 for 256-tile GEMM)
#define NKVB  (NH*(DN+DV))   // 4096
#define NTOK  (BATCH*SEQ)    // 4096
#define SCALE_F 0.07216878364870323f  // 192^-0.5
#define SCALE_LOG2E 0.10411754831420211f  // SCALE_F * log2(e)

typedef __bf16 bf16x8 __attribute__((ext_vector_type(8)));
typedef float  f32x4  __attribute__((ext_vector_type(4)));
typedef unsigned int u32x4 __attribute__((ext_vector_type(4)));
typedef unsigned short u16;
typedef unsigned short u16x4 __attribute__((ext_vector_type(4)));

__device__ __forceinline__ float b2f(u16 h) {
    unsigned int u = ((unsigned int)h) << 16;
    float f; __builtin_memcpy(&f, &u, 4); return f;
}
__device__ __forceinline__ u16 f2b(float f) {
    unsigned int x; __builtin_memcpy(&x, &f, 4);
    unsigned int r = x + 0x7fffu + ((x >> 16) & 1u);
    return (u16)(r >> 16);
}
__device__ __forceinline__ bf16x8 lds_frag(const u16* p) {
    u32x4 v = *(const u32x4*)p;
    return __builtin_bit_cast(bf16x8, v);
}
__device__ __forceinline__ bf16x8 to_frag(u32x4 v) {
    return __builtin_bit_cast(bf16x8, v);
}
__device__ __forceinline__ f32x4 mfma16(bf16x8 a, bf16x8 b, f32x4 c) {
    return __builtin_amdgcn_mfma_f32_16x16x32_bf16(a, b, c, 0, 0, 0);
}
__device__ __forceinline__ void store_out(u16* p, float v) { *p = f2b(v); }
__device__ __forceinline__ void store_out(float* p, float v) { *p = v; }
__device__ __forceinline__ void gld_lds16(const u16* g, u16* l) {
    __builtin_amdgcn_global_load_lds(
        (const __attribute__((address_space(1))) unsigned int*)g,
        (__attribute__((address_space(3))) unsigned int*)l, 16, 0, 0);
}

// ---------------- fused prep: hs cast + 4 weight transposes, one launch ----------
__global__ __launch_bounds__(256) void prep_kernel(
        const float* __restrict__ hs_f, u16* __restrict__ hs,
        const float* __restrict__ Wq, const float* __restrict__ Wkva,
        const float* __restrict__ Wkvb, const float* __restrict__ Wout,
        u16* __restrict__ WqkvT, u16* __restrict__ WkvbT, u16* __restrict__ WoutT) {
    int tid = threadIdx.x;
    int bid = blockIdx.x;
    if (bid < 8192) {            // cast: 8192*256 f32x4 = NTOK*HID elems
        int i = bid * 256 + tid;
        f32x4 v = *(const f32x4*)(hs_f + (size_t)i * 4);
        u16 o[4];
        for (int k = 0; k < 4; k++) o[k] = f2b(v[k]);
        *(unsigned long long*)(hs + (size_t)i * 4) = *(unsigned long long*)o;
        return;
    }
    bid -= 8192;
    const float* in; u16* out; int R, C, tilesC;
    if (bid < 1536)      { in = Wq;   out = WqkvT;                       R = HID;  C = NQ;   tilesC = 48; }
    else if (bid < 1920) { bid -= 1536; in = Wkva; out = WqkvT + (size_t)NQ * HID; R = HID; C = 576; tilesC = 12; }
    else if (bid < 2432) { bid -= 1920; in = Wkvb; out = WkvbT;          R = RANK; C = NKVB; tilesC = 64; }
    else                 { bid -= 2432; in = Wout; out = WoutT;          R = HID;  C = HID;  tilesC = 32; }
    __shared__ unsigned int t32[64 * 65];
    int r0 = (bid / tilesC) * 64, c0 = (bid % tilesC) * 64;
    bool valid = (c0 < C);
    for (int i = 0; i < 4; i++) {
        int u = tid + i * 256;
        int rl = u >> 4, c4 = u & 15;
        f32x4 v = {0.f, 0.f, 0.f, 0.f};
        if (valid) v = *(const f32x4*)&in[(size_t)(r0 + rl) * C + c0 + c4 * 4];
        for (int j = 0; j < 4; j++)
            t32[(c4 * 4 + j) * 65 + rl] = f2b(v[j]);
    }
    __syncthreads();
    for (int i = 0; i < 2; i++) {
        int u = tid + i * 256;
        int cl = u >> 3, r8 = (u & 7) * 8;
        unsigned int w[8];
        for (int j = 0; j < 8; j++) w[j] = t32[cl * 65 + r8 + j];
        u32x4 pk;
        for (int j = 0; j < 4; j++) pk[j] = (w[2 * j] & 0xffffu) | (w[2 * j + 1] << 16);
        *(u32x4*)&out[(size_t)(c0 + cl) * R + r0 + r8] = pk;
    }
}

// ---------------- BMx256 / BK=64 / 8-wave dbuf GEMM (T2+T3-lite+T5) ---------------
// Generalized r6 gemm256 (verified at BM=256): template BM in {256,128}.
// BM=128 -> 2 compute phases/tile, 3 half-tiles staged, LDS 96KB, grid fills all
// CUs at N=2048 (the r6 gemm_bt #9 could not use 256^2 without idling half).
template <int BM, typename OutT>
__global__ __launch_bounds__(512, 2) void gemm256k(const u16* __restrict__ A,
                                                   const u16* __restrict__ Bt,
                                                   OutT* __restrict__ C,
                                                   int K, int lda, int ldb, int ldc) {
    constexpr int MH = BM / 128;          // A half-tiles per buffer
    constexpr int NHALF = MH + 2;         // total half-tiles per dbuf slot
    __shared__ u16 lds[2 * NHALF][128 * 64];
    int tid = threadIdx.x, lane = tid & 63, w = tid >> 6;
    int wm = w >> 2, wn = w & 3;
    int g = lane >> 4, ln = lane & 15;
    int m0 = blockIdx.y * BM, n0 = blockIdx.x * 256;

    int srow = tid >> 3, schunk = tid & 7;
    int cs = schunk ^ (srow & 7);
    int sdst = tid * 8;

    auto stage = [&](int p, int ht, int t) {
        const u16* src = (ht < MH) ? A : Bt;
        int ld = (ht < MH) ? lda : ldb;
        int base = (ht < MH) ? (m0 + ht * 128) : (n0 + (ht - MH) * 128);
        u16* buf = lds[p * NHALF + ht];
        int k0 = t << 6;
        gld_lds16(&src[(size_t)(base + srow) * ld + k0 + cs * 8], &buf[sdst]);
        gld_lds16(&src[(size_t)(base + 64 + srow) * ld + k0 + cs * 8], &buf[4096 + sdst]);
    };

    int aR = ln * 64;
    int ck0 = ((g ^ (ln & 7)) << 3);
    int ck1 = (((4 + g) ^ (ln & 7)) << 3);
    int bB = (wn & 1) * 4096;
    int aBase = (BM == 256) ? 0 : wm * 4096;   // BM=128: wave M-offset inside single A half

    f32x4 acc[MH * 4][4] = {};
    int NT = K >> 6;

    // prologue: stage tile 0, publish
    for (int ht = 0; ht < NHALF; ht++) stage(0, ht, 0);
    __builtin_amdgcn_sched_barrier(0);
    asm volatile("s_waitcnt vmcnt(0)" ::: "memory");
    __builtin_amdgcn_sched_barrier(0);
    __builtin_amdgcn_s_barrier();

    for (int t = 0; t < NT; t++) {
        const u16* Ab = lds[(t & 1) * NHALF + ((BM == 256) ? wm : 0)];
        const u16* Bb = lds[(t & 1) * NHALF + MH + (wn >> 1)];
        int pn = (t & 1) ^ 1;
        bool pf = (t + 1 < NT);
        bf16x8 af[4][2], bf[4][2];

        // ---- phase 0: (Mgroup0, Nfrags0-1)
#pragma unroll
        for (int f = 0; f < 4; f++) {
            af[f][0] = lds_frag(&Ab[aBase + f * 1024 + aR + ck0]);
            af[f][1] = lds_frag(&Ab[aBase + f * 1024 + aR + ck1]);
        }
#pragma unroll
        for (int nf = 0; nf < 2; nf++) {
            bf[nf][0] = lds_frag(&Bb[bB + nf * 1024 + aR + ck0]);
            bf[nf][1] = lds_frag(&Bb[bB + nf * 1024 + aR + ck1]);
        }
        if (pf) { stage(pn, 0, t + 1); stage(pn, 1, t + 1); }
        __builtin_amdgcn_s_barrier();
        __builtin_amdgcn_s_setprio(1);
#pragma unroll
        for (int f = 0; f < 4; f++)
#pragma unroll
            for (int nf = 0; nf < 2; nf++) {
                acc[f][nf] = mfma16(af[f][0], bf[nf][0], acc[f][nf]);
                acc[f][nf] = mfma16(af[f][1], bf[nf][1], acc[f][nf]);
            }
        __builtin_amdgcn_s_setprio(0);

        // ---- phase 1: (Mgroup0, Nfrags2-3)
#pragma unroll
        for (int nf = 2; nf < 4; nf++) {
            bf[nf][0] = lds_frag(&Bb[bB + nf * 1024 + aR + ck0]);
            bf[nf][1] = lds_frag(&Bb[bB + nf * 1024 + aR + ck1]);
        }
        if (pf) { for (int ht = 2; ht < NHALF; ht++) stage(pn, ht, t + 1); }
        __builtin_amdgcn_s_barrier();
        __builtin_amdgcn_s_setprio(1);
#pragma unroll
        for (int f = 0; f < 4; f++)
#pragma unroll
            for (int nf = 2; nf < 4; nf++) {
                acc[f][nf] = mfma16(af[f][0], bf[nf][0], acc[f][nf]);
                acc[f][nf] = mfma16(af[f][1], bf[nf][1], acc[f][nf]);
            }
        __builtin_amdgcn_s_setprio(0);

        if constexpr (BM == 256) {
            // ---- phase 2: (Mhalf1, Nfrags0-1)
#pragma unroll
            for (int f = 0; f < 4; f++) {
                af[f][0] = lds_frag(&Ab[(f + 4) * 1024 + aR + ck0]);
                af[f][1] = lds_frag(&Ab[(f + 4) * 1024 + aR + ck1]);
            }
            __builtin_amdgcn_s_barrier();
            __builtin_amdgcn_s_setprio(1);
#pragma unroll
            for (int f = 0; f < 4; f++)
#pragma unroll
                for (int nf = 0; nf < 2; nf++) {
                    acc[f + 4][nf] = mfma16(af[f][0], bf[nf][0], acc[f + 4][nf]);
                    acc[f + 4][nf] = mfma16(af[f][1], bf[nf][1], acc[f + 4][nf]);
                }
            __builtin_amdgcn_s_setprio(0);

            // ---- phase 3: (Mhalf1, Nfrags2-3)
            __builtin_amdgcn_s_barrier();
            __builtin_amdgcn_s_setprio(1);
#pragma unroll
            for (int f = 0; f < 4; f++)
#pragma unroll
                for (int nf = 2; nf < 4; nf++) {
                    acc[f + 4][nf] = mfma16(af[f][0], bf[nf][0], acc[f + 4][nf]);
                    acc[f + 4][nf] = mfma16(af[f][1], bf[nf][1], acc[f + 4][nf]);
                }
            __builtin_amdgcn_s_setprio(0);
        }

        // ---- tile boundary: publish dbuf pn (per-wave drain BEFORE barrier)
        if (pf) {
            __builtin_amdgcn_sched_barrier(0);
            asm volatile("s_waitcnt vmcnt(0)" ::: "memory");
            __builtin_amdgcn_sched_barrier(0);
            __builtin_amdgcn_s_barrier();
        }
    }

    // epilogue: C write
#pragma unroll
    for (int f = 0; f < MH * 4; f++)
#pragma unroll
        for (int nf = 0; nf < 4; nf++)
#pragma unroll
            for (int r = 0; r < 4; r++) {
                int m = m0 + ((BM == 256) ? wm * 128 : wm * 64) + f * 16 + g * 4 + r;
                int n = n0 + wn * 64 + nf * 16 + ln;
                store_out(&C[(size_t)m * ldc + n], acc[f][nf][r]);
            }
}

// ---------------- RoPE on q (in-place on qkv, last 64 of each head's 192) --------
__global__ void rope_q(u16* __restrict__ qkv, const float* __restrict__ freqs) {
    int token = blockIdx.x;
    int s = token & (SEQ - 1);
    int tid = threadIdx.x;
    for (int i = 0; i < 2; i++) {
        int idx = tid + i * 256;          // 512 pairs = 16 heads * 32
        int hh = idx >> 5, p = idx & 31;
        float th = freqs[s * 32 + p];
        float c = __cosf(th), sn = __sinf(th);
        size_t off = (size_t)token * NQKV + hh * DQK + DN + 2 * p;
        float x1 = b2f(qkv[off]), x2 = b2f(qkv[off + 1]);
        qkv[off]     = f2b(x1 * c - x2 * sn);
        qkv[off + 1] = f2b(x1 * sn + x2 * c);
    }
}

// ---------------- LayerNorm over RANK cols of qkv (cols NQ..NQ+511) --------------
__global__ void ln_kv(const u16* __restrict__ qkv, const float* __restrict__ gamma,
                      const float* __restrict__ beta, u16* __restrict__ kv_c) {
    int row = blockIdx.x, tid = threadIdx.x;
    size_t base = (size_t)row * NQKV + NQ;
    float x0 = b2f(qkv[base + tid]), x1 = b2f(qkv[base + 256 + tid]);
    float s = x0 + x1, q2 = x0 * x0 + x1 * x1;
    for (int o = 32; o > 0; o >>= 1) { s += __shfl_xor(s, o); q2 += __shfl_xor(q2, o); }
    __shared__ float sh[8];
    int lane = tid & 63, w = tid >> 6;
    if (lane == 0) { sh[w] = s; sh[4 + w] = q2; }
    __syncthreads();
    float S = sh[0] + sh[1] + sh[2] + sh[3];
    float Q2 = sh[4] + sh[5] + sh[6] + sh[7];
    float mu = S * (1.f / 512.f);
    float var = Q2 * (1.f / 512.f) - mu * mu;
    float rs = rsqrtf(var + 1e-5f);
    kv_c[(size_t)row * RANK + tid] =
        f2b((x0 - mu) * rs * gamma[tid] + beta[tid]);
    kv_c[(size_t)row * RANK + 256 + tid] =
        f2b((x1 - mu) * rs * gamma[256 + tid] + beta[256 + tid]);
}

// ---------------- assemble K in SWIZZLED MFMA-FRAGMENT order -----------------------
__global__ void k_assemble(const u16* __restrict__ kvb, const u16* __restrict__ qkv,
                           const float* __restrict__ freqs, u16* __restrict__ Kf) {
    int token = blockIdx.x;
    int b = token >> 11;              // SEQ = 2048
    int s = token & (SEQ - 1);
    int tid = threadIdx.x;
    __shared__ u16 roped[64];
    if (tid < 32) {
        int p = tid;
        float th = freqs[s * 32 + p];
        float c = __cosf(th), sn = __sinf(th);
        float x1 = b2f(qkv[(size_t)token * NQKV + NQ + RANK + 2 * p]);
        float x2 = b2f(qkv[(size_t)token * NQKV + NQ + RANK + 2 * p + 1]);
        roped[2 * p]     = f2b(x1 * c - x2 * sn);
        roped[2 * p + 1] = f2b(x1 * sn + x2 * c);
    }
    __syncthreads();
    int kt = s >> 6, r = s & 63;
    int swr = ((r >> 1) & 3) * 8;     // u16-index XOR (16B-chunk swizzle)
    {   // k_nope
        int hh = tid >> 4, c8 = (tid & 15) * 8;
        size_t dst = ((size_t)(b * NH + hh) * 32 + kt) * 12288
                   + (size_t)(c8 >> 5) * 2048 + r * 32 + ((c8 & 31) ^ swr);
        *(u32x4*)&Kf[dst] = *(const u32x4*)&kvb[(size_t)token * NKVB + hh * 256 + c8];
    }
    if (tid < 128) {  // rope broadcast
        int hh = tid >> 3, c8 = (tid & 7) * 8;
        size_t dst = ((size_t)(b * NH + hh) * 32 + kt) * 12288
                   + (size_t)(4 + (c8 >> 5)) * 2048 + r * 32 + ((c8 & 31) ^ swr);
        *(u32x4*)&Kf[dst] = *(u32x4*)&roped[c8];
    }
}

// ---------------- V transpose into MFMA-FRAGMENT order ----------------------------
__global__ void v_transpose(const u16* __restrict__ kvb, u16* __restrict__ Vt) {
    __shared__ unsigned int t32[64 * 65];
    int bx = blockIdx.x;
    int st = bx * 64, dt = blockIdx.y * 64;
    int b = blockIdx.z >> 4, h = blockIdx.z & 15;
    int tid = threadIdx.x;
    for (int i = 0; i < 2; i++) {
        int u = tid + i * 256;
        int sl = u >> 3, c8 = (u & 7) * 8;
        u32x4 v = *(const u32x4*)&kvb[((size_t)(b * SEQ + st + sl) * NH + h) * 256 + DN + dt + c8];
        for (int j = 0; j < 4; j++) {
            t32[(c8 + 2 * j) * 65 + sl]     = v[j] & 0xffffu;
            t32[(c8 + 2 * j + 1) * 65 + sl] = v[j] >> 16;
        }
    }
    __syncthreads();
    for (int i = 0; i < 2; i++) {
        int u = tid + i * 256;
        int dl = u >> 3, s8 = (u & 7) * 8;
        unsigned int w[8];
        for (int j = 0; j < 8; j++) w[j] = t32[dl * 65 + s8 + j];
        u32x4 pk;
        for (int j = 0; j < 4; j++) pk[j] = (w[2 * j] & 0xffffu) | (w[2 * j + 1] << 16);
        size_t dst = ((size_t)(b * NH + h) * 32 + bx) * 8192
                   + (size_t)(s8 >> 5) * 4096 + (size_t)(dt + dl) * 32 + (s8 & 31);
        *(u32x4*)&Vt[dst] = pk;
    }
}

// ---------------- flash attention v6: addr-VALU diet + early V + raw barriers -----
// Issue-bound analysis (r6): VALU 37% dominated by ~46 addr instr/wave-iter.
// Changes vs r5: (1) V loads via 2 bumped base ptrs + offset: imm (8 asm loads,
// issued EARLY right after barrier-1 -> ~QK of latency cover; waited with counted
// vmcnt(6) after the K-DMA issue); (2) raw s_barrier + targeted lgkmcnt(0)/vmcnt
// instead of __syncthreads full drains; (3) single P buffer (safe: barrier-1
// rendezvous orders PV(t) reads (register-consumed pre-arrival) before
// softmax(t+1) writes); (4) K-DMA source pointer bumped. LDS 32.5KB.
// launch_bounds(256,3): VGPR room for qreg48+V32+oacc32 pinned (r4 lesson).
#define KC    64
#define QTILE 64
#define NIT  (SEQ / KC)
__global__ __launch_bounds__(256, 3) void attn_kernel(const u16* __restrict__ Q,
                                                      const u16* __restrict__ Kf,
                                                      const u16* __restrict__ Vt,
                                                      u16* __restrict__ O) {
    __shared__ u16 Ks[6 * 64 * 32];      // 24 KB swizzled K tile
    __shared__ u16 Ps[QTILE * 64];       // 8 KB single-buffer P (XOR-swizzled)
    __shared__ float lsumLDS[2][QTILE];  // 0.5 KB
    int tid = threadIdx.x, lane = tid & 63, w = tid >> 6;
    int w1 = w & 1;    // q 32-half
    int w2 = w >> 1;   // kv 32-half (QK) / d 64-half (PV)
    int g = lane >> 4, ln = lane & 15;
    int bid = blockIdx.x;
    int swz = ((bid & 7) << 7) | (bid >> 3);
    int qt = swz & 31, h = (swz >> 5) & 15, b = swz >> 9;

    size_t qbase = ((size_t)(b * SEQ + qt * QTILE)) * NQKV + h * DQK;
    const u16* Kh = Kf + (size_t)(b * NH + h) * (32 * 12288);
    const u16* Vh = Vt + (size_t)(b * NH + h) * (32 * 8192);

    // Q fragments -> pinned registers (opaque asm loads, no remat possible)
    u32x4 qreg[2][6];
#pragma unroll
    for (int ni = 0; ni < 2; ni++)
#pragma unroll
        for (int kk = 0; kk < 6; kk++) {
            const u16* qp = &Q[qbase + (size_t)(w1 * 32 + ni * 16 + ln) * NQKV + kk * 32 + g * 8];
            asm volatile("global_load_dwordx4 %0, %1, off"
                         : "=v"(qreg[ni][kk]) : "v"(qp));
        }
    // stage K tile 0 (linear DMA copy of pre-swizzled global image)
    const u16* kTn = Kh;
#pragma unroll
    for (int i = 0; i < 6; i++)
        gld_lds16(&kTn[i * 2048 + tid * 8], &Ks[i * 2048 + tid * 8]);

    int kRd0 = (w2 * 32 + ln) * 64 + ((g * 16) ^ (((ln >> 1) & 3) << 4));  // bytes
    int kRd1 = kRd0 + 16 * 64;
    int vrow = w2 * 2048 + ln * 32 + g * 8;   // u16
    const u16* vpA = Vh + vrow;               // kk=0 base (ni via offset: imm)
    const u16* vpB = vpA + 4096;              // kk=1 base
    int pswz = (ln & 7) << 4;

    f32x4 oacc[2][4] = {};
    float lpriv[2] = {0.f, 0.f};

    for (int kt = 0; kt < NIT; kt++) {
        // top: K-DMA(kt) is the only outstanding vmem -> drain, publish K
        asm volatile("s_waitcnt vmcnt(0)" ::: "memory");
        __builtin_amdgcn_sched_barrier(0);
        __builtin_amdgcn_s_barrier();
        // early V(kt) issue: 8 loads, 2 base ptrs + imm offsets (lands under QK)
        u32x4 v00, v01, v02, v03, v10, v11, v12, v13;
        asm volatile("global_load_dwordx4 %0, %1, off"             : "=v"(v00) : "v"(vpA));
        asm volatile("global_load_dwordx4 %0, %1, off offset:1024" : "=v"(v01) : "v"(vpA));
        asm volatile("global_load_dwordx4 %0, %1, off offset:2048" : "=v"(v02) : "v"(vpA));
        asm volatile("global_load_dwordx4 %0, %1, off offset:3072" : "=v"(v03) : "v"(vpA));
        asm volatile("global_load_dwordx4 %0, %1, off"             : "=v"(v10) : "v"(vpB));
        asm volatile("global_load_dwordx4 %0, %1, off offset:1024" : "=v"(v11) : "v"(vpB));
        asm volatile("global_load_dwordx4 %0, %1, off offset:2048" : "=v"(v12) : "v"(vpB));
        asm volatile("global_load_dwordx4 %0, %1, off offset:3072" : "=v"(v13) : "v"(vpB));
        // S^T[kv][q] = K . Q^T from LDS (conflict-free swizzled reads)
        const char* KsB = (const char*)Ks;
        f32x4 sacc[2][2] = {};
#pragma unroll
        for (int kk = 0; kk < 6; kk++) {
            bf16x8 af0 = lds_frag((const u16*)(KsB + kk * 4096 + kRd0));
            bf16x8 af1 = lds_frag((const u16*)(KsB + kk * 4096 + kRd1));
            bf16x8 q0 = to_frag(qreg[0][kk]), q1 = to_frag(qreg[1][kk]);
            sacc[0][0] = mfma16(af0, q0, sacc[0][0]);
            sacc[0][1] = mfma16(af0, q1, sacc[0][1]);
            sacc[1][0] = mfma16(af1, q0, sacc[1][0]);
            sacc[1][1] = mfma16(af1, q1, sacc[1][1]);
        }
        // exp2 + private row-sum + packed P store (cvt_pk)
        char* Pb = (char*)Ps;
#pragma unroll
        for (int mi = 0; mi < 2; mi++)
#pragma unroll
            for (int ni = 0; ni < 2; ni++) {
                float p0 = exp2f(sacc[mi][ni][0] * SCALE_LOG2E);
                float p1 = exp2f(sacc[mi][ni][1] * SCALE_LOG2E);
                float p2 = exp2f(sacc[mi][ni][2] * SCALE_LOG2E);
                float p3 = exp2f(sacc[mi][ni][3] * SCALE_LOG2E);
                lpriv[ni] += (p0 + p1) + (p2 + p3);
                unsigned int c0, c1;
                asm("v_cvt_pk_bf16_f32 %0, %1, %2" : "=v"(c0) : "v"(p0), "v"(p1));
                asm("v_cvt_pk_bf16_f32 %0, %1, %2" : "=v"(c1) : "v"(p2), "v"(p3));
                uint2 pk; pk.x = c0; pk.y = c1;
                int pwB = (w1 * 32 + ni * 16 + ln) * 128
                        + ((w2 * 64 + mi * 32 + g * 8) ^ pswz);
                *(uint2*)(Pb + pwB) = pk;
            }
        // publish P; all Ks(kt) reads consumed per-wave before arrival
        asm volatile("s_waitcnt lgkmcnt(0)" ::: "memory");
        __builtin_amdgcn_sched_barrier(0);
        __builtin_amdgcn_s_barrier();
        // issue next K-DMA (flies under PV); counted wait leaves it in flight
        if (kt + 1 < NIT) {
            kTn += 12288;
#pragma unroll
            for (int i = 0; i < 6; i++)
                gld_lds16(&kTn[i * 2048 + tid * 8], &Ks[i * 2048 + tid * 8]);
            asm volatile("s_waitcnt vmcnt(6)" ::: "memory");   // V(kt) done; DMA stays
        } else {
            asm volatile("s_waitcnt vmcnt(0)" ::: "memory");
        }
        __builtin_amdgcn_sched_barrier(0);
        // O[q][d] += P . V (P from LDS, V in regs)
        {
            bf16x8 pa0k0 = lds_frag((const u16*)(Pb + (w1 * 32 + ln) * 128 + ((g * 16) ^ pswz)));
            bf16x8 pa1k0 = lds_frag((const u16*)(Pb + (w1 * 32 + 16 + ln) * 128 + ((g * 16) ^ pswz)));
            bf16x8 pa0k1 = lds_frag((const u16*)(Pb + (w1 * 32 + ln) * 128 + ((64 + g * 16) ^ pswz)));
            bf16x8 pa1k1 = lds_frag((const u16*)(Pb + (w1 * 32 + 16 + ln) * 128 + ((64 + g * 16) ^ pswz)));
            oacc[0][0] = mfma16(pa0k0, to_frag(v00), oacc[0][0]);
            oacc[0][1] = mfma16(pa0k0, to_frag(v01), oacc[0][1]);
            oacc[0][2] = mfma16(pa0k0, to_frag(v02), oacc[0][2]);
            oacc[0][3] = mfma16(pa0k0, to_frag(v03), oacc[0][3]);
            oacc[1][0] = mfma16(pa1k0, to_frag(v00), oacc[1][0]);
            oacc[1][1] = mfma16(pa1k0, to_frag(v01), oacc[1][1]);
            oacc[1][2] = mfma16(pa1k0, to_frag(v02), oacc[1][2]);
            oacc[1][3] = mfma16(pa1k0, to_frag(v03), oacc[1][3]);
            oacc[0][0] = mfma16(pa0k1, to_frag(v10), oacc[0][0]);
            oacc[0][1] = mfma16(pa0k1, to_frag(v11), oacc[0][1]);
            oacc[0][2] = mfma16(pa0k1, to_frag(v12), oacc[0][2]);
            oacc[0][3] = mfma16(pa0k1, to_frag(v13), oacc[0][3]);
            oacc[1][0] = mfma16(pa1k1, to_frag(v10), oacc[1][0]);
            oacc[1][1] = mfma16(pa1k1, to_frag(v11), oacc[1][1]);
            oacc[1][2] = mfma16(pa1k1, to_frag(v12), oacc[1][2]);
            oacc[1][3] = mfma16(pa1k1, to_frag(v13), oacc[1][3]);
        }
        vpA += 8192; vpB += 8192;
    }

    // final lsum reduction
    for (int ni = 0; ni < 2; ni++) {
        float v = lpriv[ni];
        v += __shfl_xor(v, 16);
        v += __shfl_xor(v, 32);
        if (g == 0) lsumLDS[w2][w1 * 32 + ni * 16 + ln] = v;
    }
    __syncthreads();
    for (int mi = 0; mi < 2; mi++)
        for (int ni = 0; ni < 4; ni++) {
            int d = w2 * 64 + ni * 16 + ln;
            for (int r = 0; r < 4; r++) {
                int row = w1 * 32 + mi * 16 + g * 4 + r;
                float l = lsumLDS[0][row] + lsumLDS[1][row];
                O[((size_t)(b * SEQ + qt * QTILE + row) * NH + h) * DV + d] =
                    f2b(oacc[mi][ni][r] / l);
            }
        }
}

// ---------------- launcher ----------------
extern "C" void kernel_launch(void* const* d_in, const int* in_sizes, int n_in,
                              void* d_out, int out_size, void* d_ws, size_t ws_size,
                              hipStream_t stream) {
    const float* hs_f  = (const float*)d_in[0];
    const float* freqs = (const float*)d_in[1];
    const float* Wq    = (const float*)d_in[2];
    const float* Wkva  = (const float*)d_in[3];
    const float* gamma = (const float*)d_in[4];
    const float* beta  = (const float*)d_in[5];
    const float* Wkvb  = (const float*)d_in[6];
    const float* Wout  = (const float*)d_in[7];
    float* outp = (float*)d_out;

    char* ws = (char*)d_ws;
    size_t off = 0;
    auto alloc = [&](size_t elems) -> u16* {
        u16* p = (u16*)(ws + off);
        off += ((elems * 2 + 255) / 256) * 256;
        return p;
    };
    u16* hs     = alloc((size_t)NTOK * HID);
    u16* WqkvT  = alloc((size_t)NQKV * HID);
    u16* WkvbT  = alloc((size_t)NKVB * RANK);
    u16* WoutT  = alloc((size_t)HID * HID);
    u16* qkv    = alloc((size_t)NTOK * NQKV);
    u16* kv_c   = alloc((size_t)NTOK * RANK);
    u16* kvb    = alloc((size_t)NTOK * NKVB);
    u16* Kf     = alloc((size_t)NTOK * NQ);
    u16* Vt     = alloc((size_t)BATCH * NH * DV * SEQ);
    u16* attn   = alloc((size_t)NTOK * NH * DV);
    (void)ws_size; (void)in_sizes; (void)n_in; (void)out_size;

    // 1. fused prep: cast + all weight transposes
    prep_kernel<<<8192 + 1536 + 384 + 512 + 1024, 256, 0, stream>>>(
        hs_f, hs, Wq, Wkva, Wkvb, Wout, WqkvT, WkvbT, WoutT);

    // 2. fused q + kv_a GEMM: (4096 x 3840 x 2048) on 256^2 8-wave kernel
    gemm256k<256><<<dim3(NQKV / 256, NTOK / 256), 512, 0, stream>>>(hs, WqkvT, qkv, HID, HID, HID, NQKV);

    // 3. RoPE on q (in place)
    rope_q<<<NTOK, 256, 0, stream>>>(qkv, freqs);

    // 4. layernorm
    ln_kv<<<NTOK, 256, 0, stream>>>(qkv, gamma, beta, kv_c);

    // 5. kvb = kv_c @ Wkv_b (4096 x 4096 x 512) on 256^2 kernel
    gemm256k<256><<<dim3(NKVB / 256, NTOK / 256), 512, 0, stream>>>(kv_c, WkvbT, kvb, RANK, RANK, RANK, NKVB);

    // 6. K assembly (swizzled fragment-order)
    k_assemble<<<NTOK, 256, 0, stream>>>(kvb, qkv, freqs, Kf);

    // 7. V transpose (fragment-order)
    v_transpose<<<dim3(SEQ / 64, DV / 64, BATCH * NH), 256, 0, stream>>>(kvb, Vt);

    // 8. attention (v6)
    attn_kernel<<<1024, 256, 0, stream>>>(qkv, Kf, Vt, attn);

    // 9. out = attn @ Wout (4096 x 2048 x 2048) on 128x256 tile: grid 8x32 = 256
    //    blocks = exactly 1/CU (256^2 at N=2048 would idle half the CUs)
    gemm256k<128><<<dim3(HID / 256, NTOK / 128), 512, 0, stream>>>(attn, WoutT, outp, HID, HID, HID, HID);
}

// Round 8
// 413.289 us; speedup vs baseline: 1.2253x; 1.0162x over previous
//
#include <hip/hip_runtime.h>

// ---------------- constants ----------------
#define BATCH 2
#define SEQ   2048
#define HID   2048
#define NH    16
#define DN    128
#define DR    64
#define DV    128
#define RANK  512
#define DQK   192            // DN + DR
#define NQ    (NH*DQK)       // 3072
#define NQKV  3840           // NQ + 768 pad (= 15*256 for 256-tile GEMM)
#define NKVB  (NH*(DN+DV))   // 4096
#define NTOK  (BATCH*SEQ)    // 4096
#define SCALE_F 0.07216878364870323f  // 192^-0.5
#define SCALE_LOG2E 0.10411754831420211f  // SCALE_F * log2(e)

typedef __bf16 bf16x8 __attribute__((ext_vector_type(8)));
typedef float  f32x4  __attribute__((ext_vector_type(4)));
typedef unsigned int u32x4 __attribute__((ext_vector_type(4)));
typedef unsigned short u16;
typedef unsigned short u16x4 __attribute__((ext_vector_type(4)));

__device__ __forceinline__ float b2f(u16 h) {
    unsigned int u = ((unsigned int)h) << 16;
    float f; __builtin_memcpy(&f, &u, 4); return f;
}
__device__ __forceinline__ u16 f2b(float f) {
    unsigned int x; __builtin_memcpy(&x, &f, 4);
    unsigned int r = x + 0x7fffu + ((x >> 16) & 1u);
    return (u16)(r >> 16);
}
__device__ __forceinline__ bf16x8 lds_frag(const u16* p) {
    u32x4 v = *(const u32x4*)p;
    return __builtin_bit_cast(bf16x8, v);
}
__device__ __forceinline__ bf16x8 to_frag(u32x4 v) {
    return __builtin_bit_cast(bf16x8, v);
}
__device__ __forceinline__ f32x4 mfma16(bf16x8 a, bf16x8 b, f32x4 c) {
    return __builtin_amdgcn_mfma_f32_16x16x32_bf16(a, b, c, 0, 0, 0);
}
__device__ __forceinline__ void store_out(u16* p, float v) { *p = f2b(v); }
__device__ __forceinline__ void store_out(float* p, float v) { *p = v; }
__device__ __forceinline__ void gld_lds16(const u16* g, u16* l) {
    __builtin_amdgcn_global_load_lds(
        (const __attribute__((address_space(1))) unsigned int*)g,
        (__attribute__((address_space(3))) unsigned int*)l, 16, 0, 0);
}

// ---------------- fused prep: hs cast + 4 weight transposes, one launch ----------
__global__ __launch_bounds__(256) void prep_kernel(
        const float* __restrict__ hs_f, u16* __restrict__ hs,
        const float* __restrict__ Wq, const float* __restrict__ Wkva,
        const float* __restrict__ Wkvb, const float* __restrict__ Wout,
        u16* __restrict__ WqkvT, u16* __restrict__ WkvbT, u16* __restrict__ WoutT) {
    int tid = threadIdx.x;
    int bid = blockIdx.x;
    if (bid < 8192) {            // cast: 8192*256 f32x4 = NTOK*HID elems
        int i = bid * 256 + tid;
        f32x4 v = *(const f32x4*)(hs_f + (size_t)i * 4);
        u16 o[4];
        for (int k = 0; k < 4; k++) o[k] = f2b(v[k]);
        *(unsigned long long*)(hs + (size_t)i * 4) = *(unsigned long long*)o;
        return;
    }
    bid -= 8192;
    const float* in; u16* out; int R, C, tilesC;
    if (bid < 1536)      { in = Wq;   out = WqkvT;                       R = HID;  C = NQ;   tilesC = 48; }
    else if (bid < 1920) { bid -= 1536; in = Wkva; out = WqkvT + (size_t)NQ * HID; R = HID; C = 576; tilesC = 12; }
    else if (bid < 2432) { bid -= 1920; in = Wkvb; out = WkvbT;          R = RANK; C = NKVB; tilesC = 64; }
    else                 { bid -= 2432; in = Wout; out = WoutT;          R = HID;  C = HID;  tilesC = 32; }
    __shared__ unsigned int t32[64 * 65];
    int r0 = (bid / tilesC) * 64, c0 = (bid % tilesC) * 64;
    bool valid = (c0 < C);
    for (int i = 0; i < 4; i++) {
        int u = tid + i * 256;
        int rl = u >> 4, c4 = u & 15;
        f32x4 v = {0.f, 0.f, 0.f, 0.f};
        if (valid) v = *(const f32x4*)&in[(size_t)(r0 + rl) * C + c0 + c4 * 4];
        for (int j = 0; j < 4; j++)
            t32[(c4 * 4 + j) * 65 + rl] = f2b(v[j]);
    }
    __syncthreads();
    for (int i = 0; i < 2; i++) {
        int u = tid + i * 256;
        int cl = u >> 3, r8 = (u & 7) * 8;
        unsigned int w[8];
        for (int j = 0; j < 8; j++) w[j] = t32[cl * 65 + r8 + j];
        u32x4 pk;
        for (int j = 0; j < 4; j++) pk[j] = (w[2 * j] & 0xffffu) | (w[2 * j + 1] << 16);
        *(u32x4*)&out[(size_t)(c0 + cl) * R + r0 + r8] = pk;
    }
}

// ---------------- BMx256 / BK=64 / 8-wave dbuf GEMM (T2+T3-lite+T5) ---------------
template <int BM, typename OutT>
__global__ __launch_bounds__(512, 2) void gemm256k(const u16* __restrict__ A,
                                                   const u16* __restrict__ Bt,
                                                   OutT* __restrict__ C,
                                                   int K, int lda, int ldb, int ldc) {
    constexpr int MH = BM / 128;          // A half-tiles per buffer
    constexpr int NHALF = MH + 2;         // total half-tiles per dbuf slot
    __shared__ u16 lds[2 * NHALF][128 * 64];
    int tid = threadIdx.x, lane = tid & 63, w = tid >> 6;
    int wm = w >> 2, wn = w & 3;
    int g = lane >> 4, ln = lane & 15;
    int m0 = blockIdx.y * BM, n0 = blockIdx.x * 256;

    int srow = tid >> 3, schunk = tid & 7;
    int cs = schunk ^ (srow & 7);
    int sdst = tid * 8;

    auto stage = [&](int p, int ht, int t) {
        const u16* src = (ht < MH) ? A : Bt;
        int ld = (ht < MH) ? lda : ldb;
        int base = (ht < MH) ? (m0 + ht * 128) : (n0 + (ht - MH) * 128);
        u16* buf = lds[p * NHALF + ht];
        int k0 = t << 6;
        gld_lds16(&src[(size_t)(base + srow) * ld + k0 + cs * 8], &buf[sdst]);
        gld_lds16(&src[(size_t)(base + 64 + srow) * ld + k0 + cs * 8], &buf[4096 + sdst]);
    };

    int aR = ln * 64;
    int ck0 = ((g ^ (ln & 7)) << 3);
    int ck1 = (((4 + g) ^ (ln & 7)) << 3);
    int bB = (wn & 1) * 4096;
    int aBase = (BM == 256) ? 0 : wm * 4096;

    f32x4 acc[MH * 4][4] = {};
    int NT = K >> 6;

    // prologue: stage tile 0, publish
    for (int ht = 0; ht < NHALF; ht++) stage(0, ht, 0);
    __builtin_amdgcn_sched_barrier(0);
    asm volatile("s_waitcnt vmcnt(0)" ::: "memory");
    __builtin_amdgcn_sched_barrier(0);
    __builtin_amdgcn_s_barrier();

    for (int t = 0; t < NT; t++) {
        const u16* Ab = lds[(t & 1) * NHALF + ((BM == 256) ? wm : 0)];
        const u16* Bb = lds[(t & 1) * NHALF + MH + (wn >> 1)];
        int pn = (t & 1) ^ 1;
        bool pf = (t + 1 < NT);
        bf16x8 af[4][2], bf[4][2];

        // ---- phase 0: (Mgroup0, Nfrags0-1)
#pragma unroll
        for (int f = 0; f < 4; f++) {
            af[f][0] = lds_frag(&Ab[aBase + f * 1024 + aR + ck0]);
            af[f][1] = lds_frag(&Ab[aBase + f * 1024 + aR + ck1]);
        }
#pragma unroll
        for (int nf = 0; nf < 2; nf++) {
            bf[nf][0] = lds_frag(&Bb[bB + nf * 1024 + aR + ck0]);
            bf[nf][1] = lds_frag(&Bb[bB + nf * 1024 + aR + ck1]);
        }
        if (pf) { stage(pn, 0, t + 1); stage(pn, 1, t + 1); }
        __builtin_amdgcn_s_barrier();
        __builtin_amdgcn_s_setprio(1);
#pragma unroll
        for (int f = 0; f < 4; f++)
#pragma unroll
            for (int nf = 0; nf < 2; nf++) {
                acc[f][nf] = mfma16(af[f][0], bf[nf][0], acc[f][nf]);
                acc[f][nf] = mfma16(af[f][1], bf[nf][1], acc[f][nf]);
            }
        __builtin_amdgcn_s_setprio(0);

        // ---- phase 1: (Mgroup0, Nfrags2-3)
#pragma unroll
        for (int nf = 2; nf < 4; nf++) {
            bf[nf][0] = lds_frag(&Bb[bB + nf * 1024 + aR + ck0]);
            bf[nf][1] = lds_frag(&Bb[bB + nf * 1024 + aR + ck1]);
        }
        if (pf) { for (int ht = 2; ht < NHALF; ht++) stage(pn, ht, t + 1); }
        __builtin_amdgcn_s_barrier();
        __builtin_amdgcn_s_setprio(1);
#pragma unroll
        for (int f = 0; f < 4; f++)
#pragma unroll
            for (int nf = 2; nf < 4; nf++) {
                acc[f][nf] = mfma16(af[f][0], bf[nf][0], acc[f][nf]);
                acc[f][nf] = mfma16(af[f][1], bf[nf][1], acc[f][nf]);
            }
        __builtin_amdgcn_s_setprio(0);

        if constexpr (BM == 256) {
            // ---- phase 2: (Mhalf1, Nfrags0-1)
#pragma unroll
            for (int f = 0; f < 4; f++) {
                af[f][0] = lds_frag(&Ab[(f + 4) * 1024 + aR + ck0]);
                af[f][1] = lds_frag(&Ab[(f + 4) * 1024 + aR + ck1]);
            }
            __builtin_amdgcn_s_barrier();
            __builtin_amdgcn_s_setprio(1);
#pragma unroll
            for (int f = 0; f < 4; f++)
#pragma unroll
                for (int nf = 0; nf < 2; nf++) {
                    acc[f + 4][nf] = mfma16(af[f][0], bf[nf][0], acc[f + 4][nf]);
                    acc[f + 4][nf] = mfma16(af[f][1], bf[nf][1], acc[f + 4][nf]);
                }
            __builtin_amdgcn_s_setprio(0);

            // ---- phase 3: (Mhalf1, Nfrags2-3)
            __builtin_amdgcn_s_barrier();
            __builtin_amdgcn_s_setprio(1);
#pragma unroll
            for (int f = 0; f < 4; f++)
#pragma unroll
                for (int nf = 2; nf < 4; nf++) {
                    acc[f + 4][nf] = mfma16(af[f][0], bf[nf][0], acc[f + 4][nf]);
                    acc[f + 4][nf] = mfma16(af[f][1], bf[nf][1], acc[f + 4][nf]);
                }
            __builtin_amdgcn_s_setprio(0);
        }

        // ---- tile boundary: publish dbuf pn (per-wave drain BEFORE barrier)
        if (pf) {
            __builtin_amdgcn_sched_barrier(0);
            asm volatile("s_waitcnt vmcnt(0)" ::: "memory");
            __builtin_amdgcn_sched_barrier(0);
            __builtin_amdgcn_s_barrier();
        }
    }

    // epilogue: C write
#pragma unroll
    for (int f = 0; f < MH * 4; f++)
#pragma unroll
        for (int nf = 0; nf < 4; nf++)
#pragma unroll
            for (int r = 0; r < 4; r++) {
                int m = m0 + ((BM == 256) ? wm * 128 : wm * 64) + f * 16 + g * 4 + r;
                int n = n0 + wn * 64 + nf * 16 + ln;
                store_out(&C[(size_t)m * ldc + n], acc[f][nf][r]);
            }
}

// ---------------- fused RoPE(q) + LayerNorm(kv_a) — disjoint qkv columns ----------
__global__ void rope_ln(u16* __restrict__ qkv, const float* __restrict__ freqs,
                        const float* __restrict__ gamma, const float* __restrict__ beta,
                        u16* __restrict__ kv_c) {
    int token = blockIdx.x;
    int s = token & (SEQ - 1);
    int tid = threadIdx.x;
    // --- RoPE on q (cols h*DQK+128..h*DQK+192): 512 pairs
    for (int i = 0; i < 2; i++) {
        int idx = tid + i * 256;
        int hh = idx >> 5, p = idx & 31;
        float th = freqs[s * 32 + p];
        float c = __cosf(th), sn = __sinf(th);
        size_t off = (size_t)token * NQKV + hh * DQK + DN + 2 * p;
        float x1 = b2f(qkv[off]), x2 = b2f(qkv[off + 1]);
        qkv[off]     = f2b(x1 * c - x2 * sn);
        qkv[off + 1] = f2b(x1 * sn + x2 * c);
    }
    // --- LayerNorm over cols NQ..NQ+511 (independent of the RoPE region)
    size_t base = (size_t)token * NQKV + NQ;
    float x0 = b2f(qkv[base + tid]), x1 = b2f(qkv[base + 256 + tid]);
    float sm = x0 + x1, q2 = x0 * x0 + x1 * x1;
    for (int o = 32; o > 0; o >>= 1) { sm += __shfl_xor(sm, o); q2 += __shfl_xor(q2, o); }
    __shared__ float sh[8];
    int lane = tid & 63, w = tid >> 6;
    if (lane == 0) { sh[w] = sm; sh[4 + w] = q2; }
    __syncthreads();
    float S = sh[0] + sh[1] + sh[2] + sh[3];
    float Q2 = sh[4] + sh[5] + sh[6] + sh[7];
    float mu = S * (1.f / 512.f);
    float var = Q2 * (1.f / 512.f) - mu * mu;
    float rs = rsqrtf(var + 1e-5f);
    kv_c[(size_t)token * RANK + tid] =
        f2b((x0 - mu) * rs * gamma[tid] + beta[tid]);
    kv_c[(size_t)token * RANK + 256 + tid] =
        f2b((x1 - mu) * rs * gamma[256 + tid] + beta[256 + tid]);
}

// ---------------- fused K assembly + V transpose (block-id split) -----------------
// bid < NTOK: K assembly into SWIZZLED MFMA-fragment order
//   Kf: [b][h][kt=32][kk=6][r=64][c=32], chunk swizzle (c8 ^ ((r>>1&3)*8)) baked in.
// bid >= NTOK: V transpose into fragment order
//   Vt: [b][h][st=32][kk=2][dr=128][c=32].
__global__ void kv_prep(const u16* __restrict__ kvb, const u16* __restrict__ qkv,
                        const float* __restrict__ freqs, u16* __restrict__ Kf,
                        u16* __restrict__ Vt) {
    __shared__ unsigned int t32[64 * 65];
    int bid = blockIdx.x;
    int tid = threadIdx.x;
    if (bid < NTOK) {
        int token = bid;
        int b = token >> 11;
        int s = token & (SEQ - 1);
        u16* roped = (u16*)t32;
        if (tid < 32) {
            int p = tid;
            float th = freqs[s * 32 + p];
            float c = __cosf(th), sn = __sinf(th);
            float x1 = b2f(qkv[(size_t)token * NQKV + NQ + RANK + 2 * p]);
            float x2 = b2f(qkv[(size_t)token * NQKV + NQ + RANK + 2 * p + 1]);
            roped[2 * p]     = f2b(x1 * c - x2 * sn);
            roped[2 * p + 1] = f2b(x1 * sn + x2 * c);
        }
        __syncthreads();
        int kt = s >> 6, r = s & 63;
        int swr = ((r >> 1) & 3) * 8;
        {   // k_nope
            int hh = tid >> 4, c8 = (tid & 15) * 8;
            size_t dst = ((size_t)(b * NH + hh) * 32 + kt) * 12288
                       + (size_t)(c8 >> 5) * 2048 + r * 32 + ((c8 & 31) ^ swr);
            *(u32x4*)&Kf[dst] = *(const u32x4*)&kvb[(size_t)token * NKVB + hh * 256 + c8];
        }
        if (tid < 128) {  // rope broadcast
            int hh = tid >> 3, c8 = (tid & 7) * 8;
            size_t dst = ((size_t)(b * NH + hh) * 32 + kt) * 12288
                       + (size_t)(4 + (c8 >> 5)) * 2048 + r * 32 + ((c8 & 31) ^ swr);
            *(u32x4*)&Kf[dst] = *(u32x4*)&roped[c8];
        }
        return;
    }
    // ---- V transpose part
    int rblk = bid - NTOK;                 // [0, 2048)
    int bx = rblk & 31;                    // s-tile
    int by = (rblk >> 5) & 1;              // d-tile
    int bz = rblk >> 6;                    // b*NH+h
    int st = bx * 64, dt = by * 64;
    int b = bz >> 4, h = bz & 15;
    for (int i = 0; i < 2; i++) {
        int u = tid + i * 256;
        int sl = u >> 3, c8 = (u & 7) * 8;
        u32x4 v = *(const u32x4*)&kvb[((size_t)(b * SEQ + st + sl) * NH + h) * 256 + DN + dt + c8];
        for (int j = 0; j < 4; j++) {
            t32[(c8 + 2 * j) * 65 + sl]     = v[j] & 0xffffu;
            t32[(c8 + 2 * j + 1) * 65 + sl] = v[j] >> 16;
        }
    }
    __syncthreads();
    for (int i = 0; i < 2; i++) {
        int u = tid + i * 256;
        int dl = u >> 3, s8 = (u & 7) * 8;
        unsigned int w[8];
        for (int j = 0; j < 8; j++) w[j] = t32[dl * 65 + s8 + j];
        u32x4 pk;
        for (int j = 0; j < 4; j++) pk[j] = (w[2 * j] & 0xffffu) | (w[2 * j + 1] << 16);
        size_t dst = ((size_t)(b * NH + h) * 32 + bx) * 8192
                   + (size_t)(s8 >> 5) * 4096 + (size_t)(dt + dl) * 32 + (s8 & 31);
        *(u32x4*)&Vt[dst] = pk;
    }
}

// ---------------- flash attention (r6-exact: 142 us verified) ---------------------
// K via gld_lds DMA (pre-swizzled global image), V direct-from-L2 fragment order,
// Q asm-pinned, double-buffered P, 2 syncthreads/iter, XCD-swizzled 1D grid.
#define KC    64
#define QTILE 64
#define NIT  (SEQ / KC)
__global__ __launch_bounds__(256, 4) void attn_kernel(const u16* __restrict__ Q,
                                                      const u16* __restrict__ Kf,
                                                      const u16* __restrict__ Vt,
                                                      u16* __restrict__ O) {
    __shared__ u16 Ks[6 * 64 * 32];      // 24 KB swizzled K tile
    __shared__ u16 Ps[2][QTILE * 64];    // 16 KB double-buffered P (XOR-swizzled)
    int tid = threadIdx.x, lane = tid & 63, w = tid >> 6;
    int w1 = w & 1;    // q 32-half
    int w2 = w >> 1;   // kv 32-half (QK) / d 64-half (PV)
    int g = lane >> 4, ln = lane & 15;
    int bid = blockIdx.x;
    int swz = ((bid & 7) << 7) | (bid >> 3);
    int qt = swz & 31, h = (swz >> 5) & 15, b = swz >> 9;

    size_t qbase = ((size_t)(b * SEQ + qt * QTILE)) * NQKV + h * DQK;
    const u16* Kh = Kf + (size_t)(b * NH + h) * (32 * 12288);
    const u16* Vh = Vt + (size_t)(b * NH + h) * (32 * 8192);

    // Q fragments -> pinned registers (opaque asm loads, no remat possible)
    u32x4 qreg[2][6];
#pragma unroll
    for (int ni = 0; ni < 2; ni++)
#pragma unroll
        for (int kk = 0; kk < 6; kk++) {
            const u16* qp = &Q[qbase + (size_t)(w1 * 32 + ni * 16 + ln) * NQKV + kk * 32 + g * 8];
            asm volatile("global_load_dwordx4 %0, %1, off"
                         : "=v"(qreg[ni][kk]) : "v"(qp));
        }
    // stage K tile 0 (linear DMA copy of pre-swizzled global image)
#pragma unroll
    for (int i = 0; i < 6; i++)
        gld_lds16(&Kh[i * 2048 + tid * 8], &Ks[i * 2048 + tid * 8]);

    int kRd0 = (w2 * 32 + ln) * 64 + ((g * 16) ^ (((ln >> 1) & 3) << 4));  // bytes
    int kRd1 = kRd0 + 16 * 64;
    int vrow = w2 * 2048 + ln * 32 + g * 8;   // u16, + kk*4096 + ni*512
    int pswz = (ln & 7) << 4;

    f32x4 oacc[2][4] = {};
    float lpriv[2] = {0.f, 0.f};

    for (int kt = 0; kt < NIT; kt++) {
        asm volatile("s_waitcnt vmcnt(0)" ::: "memory");
        __builtin_amdgcn_sched_barrier(0);
        __syncthreads();                   // K(kt) visible to all waves
        const char* KsB = (const char*)Ks;
        f32x4 sacc[2][2] = {};
#pragma unroll
        for (int kk = 0; kk < 6; kk++) {
            bf16x8 af0 = lds_frag((const u16*)(KsB + kk * 4096 + kRd0));
            bf16x8 af1 = lds_frag((const u16*)(KsB + kk * 4096 + kRd1));
            bf16x8 q0 = to_frag(qreg[0][kk]), q1 = to_frag(qreg[1][kk]);
            sacc[0][0] = mfma16(af0, q0, sacc[0][0]);
            sacc[0][1] = mfma16(af0, q1, sacc[0][1]);
            sacc[1][0] = mfma16(af1, q0, sacc[1][0]);
            sacc[1][1] = mfma16(af1, q1, sacc[1][1]);
        }
        char* Pb = (char*)Ps[kt & 1];
#pragma unroll
        for (int mi = 0; mi < 2; mi++)
#pragma unroll
            for (int ni = 0; ni < 2; ni++) {
                float p0 = exp2f(sacc[mi][ni][0] * SCALE_LOG2E);
                float p1 = exp2f(sacc[mi][ni][1] * SCALE_LOG2E);
                float p2 = exp2f(sacc[mi][ni][2] * SCALE_LOG2E);
                float p3 = exp2f(sacc[mi][ni][3] * SCALE_LOG2E);
                lpriv[ni] += (p0 + p1) + (p2 + p3);
                unsigned int c0, c1;
                asm("v_cvt_pk_bf16_f32 %0, %1, %2" : "=v"(c0) : "v"(p0), "v"(p1));
                asm("v_cvt_pk_bf16_f32 %0, %1, %2" : "=v"(c1) : "v"(p2), "v"(p3));
                uint2 pk; pk.x = c0; pk.y = c1;
                int pwB = (w1 * 32 + ni * 16 + ln) * 128
                        + ((w2 * 64 + mi * 32 + g * 8) ^ pswz);
                *(uint2*)(Pb + pwB) = pk;
            }
        __syncthreads();                   // P(kt) ready; K(kt) reads done
        if (kt + 1 < NIT) {
            const u16* kT = Kh + (size_t)(kt + 1) * 12288;
#pragma unroll
            for (int i = 0; i < 6; i++)
                gld_lds16(&kT[i * 2048 + tid * 8], &Ks[i * 2048 + tid * 8]);
        }
        const u16* vT = Vh + (size_t)kt * 8192;
#pragma unroll
        for (int kk = 0; kk < 2; kk++) {
            bf16x8 pa[2], vb[4];
#pragma unroll
            for (int mi = 0; mi < 2; mi++)
                pa[mi] = lds_frag((const u16*)(Pb + (w1 * 32 + mi * 16 + ln) * 128
                                               + ((kk * 64 + g * 16) ^ pswz)));
#pragma unroll
            for (int ni = 0; ni < 4; ni++)
                vb[ni] = to_frag(*(const u32x4*)&vT[kk * 4096 + ni * 512 + vrow]);
#pragma unroll
            for (int mi = 0; mi < 2; mi++)
#pragma unroll
                for (int ni = 0; ni < 4; ni++)
                    oacc[mi][ni] = mfma16(pa[mi], vb[ni], oacc[mi][ni]);
        }
    }

    float* lsumF = (float*)Ps[0];
    for (int ni = 0; ni < 2; ni++) {
        float v = lpriv[ni];
        v += __shfl_xor(v, 16);
        v += __shfl_xor(v, 32);
        if (g == 0) lsumF[w2 * 64 + w1 * 32 + ni * 16 + ln] = v;
    }
    __syncthreads();
    for (int mi = 0; mi < 2; mi++)
        for (int ni = 0; ni < 4; ni++) {
            int d = w2 * 64 + ni * 16 + ln;
            for (int r = 0; r < 4; r++) {
                int row = w1 * 32 + mi * 16 + g * 4 + r;
                float l = lsumF[row] + lsumF[64 + row];
                O[((size_t)(b * SEQ + qt * QTILE + row) * NH + h) * DV + d] =
                    f2b(oacc[mi][ni][r] / l);
            }
        }
}

// ---------------- launcher ----------------
extern "C" void kernel_launch(void* const* d_in, const int* in_sizes, int n_in,
                              void* d_out, int out_size, void* d_ws, size_t ws_size,
                              hipStream_t stream) {
    const float* hs_f  = (const float*)d_in[0];
    const float* freqs = (const float*)d_in[1];
    const float* Wq    = (const float*)d_in[2];
    const float* Wkva  = (const float*)d_in[3];
    const float* gamma = (const float*)d_in[4];
    const float* beta  = (const float*)d_in[5];
    const float* Wkvb  = (const float*)d_in[6];
    const float* Wout  = (const float*)d_in[7];
    float* outp = (float*)d_out;

    char* ws = (char*)d_ws;
    size_t off = 0;
    auto alloc = [&](size_t elems) -> u16* {
        u16* p = (u16*)(ws + off);
        off += ((elems * 2 + 255) / 256) * 256;
        return p;
    };
    u16* hs     = alloc((size_t)NTOK * HID);
    u16* WqkvT  = alloc((size_t)NQKV * HID);
    u16* WkvbT  = alloc((size_t)NKVB * RANK);
    u16* WoutT  = alloc((size_t)HID * HID);
    u16* qkv    = alloc((size_t)NTOK * NQKV);
    u16* kv_c   = alloc((size_t)NTOK * RANK);
    u16* kvb    = alloc((size_t)NTOK * NKVB);
    u16* Kf     = alloc((size_t)NTOK * NQ);
    u16* Vt     = alloc((size_t)BATCH * NH * DV * SEQ);
    u16* attn   = alloc((size_t)NTOK * NH * DV);
    (void)ws_size; (void)in_sizes; (void)n_in; (void)out_size;

    // 1. fused prep: cast + all weight transposes
    prep_kernel<<<8192 + 1536 + 384 + 512 + 1024, 256, 0, stream>>>(
        hs_f, hs, Wq, Wkva, Wkvb, Wout, WqkvT, WkvbT, WoutT);

    // 2. fused q + kv_a GEMM: (4096 x 3840 x 2048) on 256^2 8-wave kernel
    gemm256k<256><<<dim3(NQKV / 256, NTOK / 256), 512, 0, stream>>>(hs, WqkvT, qkv, HID, HID, HID, NQKV);

    // 3. fused RoPE(q) + LayerNorm(kv_a)
    rope_ln<<<NTOK, 256, 0, stream>>>(qkv, freqs, gamma, beta, kv_c);

    // 4. kvb = kv_c @ Wkv_b (4096 x 4096 x 512) on 256^2 kernel
    gemm256k<256><<<dim3(NKVB / 256, NTOK / 256), 512, 0, stream>>>(kv_c, WkvbT, kvb, RANK, RANK, RANK, NKVB);

    // 5. fused K assembly + V transpose
    kv_prep<<<NTOK + 2048, 256, 0, stream>>>(kvb, qkv, freqs, Kf, Vt);

    // 6. attention (r6-exact kernel)
    attn_kernel<<<1024, 256, 0, stream>>>(qkv, Kf, Vt, attn);

    // 7. out = attn @ Wout (4096 x 2048 x 2048) on 128x256 tile (256 blocks = 1/CU)
    gemm256k<128><<<dim3(HID / 256, NTOK / 128), 512, 0, stream>>>(attn, WoutT, outp, HID, HID, HID, HID);
}

// Round 9
// 401.867 us; speedup vs baseline: 1.2601x; 1.0284x over previous
//
#include <hip/hip_runtime.h>

// ---------------- constants ----------------
#define BATCH 2
#define SEQ   2048
#define HID   2048
#define NH    16
#define DN    128
#define DR    64
#define DV    128
#define RANK  512
#define DQK   192            // DN + DR
#define NQ    (NH*DQK)       // 3072
#define NQKV  3840           // NQ + 768 pad (= 15*256 for 256-tile GEMM)
#define NKVB  (NH*(DN+DV))   // 4096
#define NTOK  (BATCH*SEQ)    // 4096
#define SCALE_F 0.07216878364870323f  // 192^-0.5
#define SCALE_LOG2E 0.10411754831420211f  // SCALE_F * log2(e)

typedef __bf16 bf16x8 __attribute__((ext_vector_type(8)));
typedef float  f32x4  __attribute__((ext_vector_type(4)));
typedef unsigned int u32x4 __attribute__((ext_vector_type(4)));
typedef unsigned short u16;
typedef unsigned short u16x4 __attribute__((ext_vector_type(4)));

__device__ __forceinline__ float b2f(u16 h) {
    unsigned int u = ((unsigned int)h) << 16;
    float f; __builtin_memcpy(&f, &u, 4); return f;
}
__device__ __forceinline__ u16 f2b(float f) {
    unsigned int x; __builtin_memcpy(&x, &f, 4);
    unsigned int r = x + 0x7fffu + ((x >> 16) & 1u);
    return (u16)(r >> 16);
}
__device__ __forceinline__ bf16x8 lds_frag(const u16* p) {
    u32x4 v = *(const u32x4*)p;
    return __builtin_bit_cast(bf16x8, v);
}
__device__ __forceinline__ bf16x8 to_frag(u32x4 v) {
    return __builtin_bit_cast(bf16x8, v);
}
__device__ __forceinline__ f32x4 mfma16(bf16x8 a, bf16x8 b, f32x4 c) {
    return __builtin_amdgcn_mfma_f32_16x16x32_bf16(a, b, c, 0, 0, 0);
}
__device__ __forceinline__ void store_out(u16* p, float v) { *p = f2b(v); }
__device__ __forceinline__ void store_out(float* p, float v) { *p = v; }
__device__ __forceinline__ void gld_lds16(const u16* g, u16* l) {
    __builtin_amdgcn_global_load_lds(
        (const __attribute__((address_space(1))) unsigned int*)g,
        (__attribute__((address_space(3))) unsigned int*)l, 16, 0, 0);
}

// ---------------- fused prep: hs cast + 4 weight transposes, one launch ----------
__global__ __launch_bounds__(256) void prep_kernel(
        const float* __restrict__ hs_f, u16* __restrict__ hs,
        const float* __restrict__ Wq, const float* __restrict__ Wkva,
        const float* __restrict__ Wkvb, const float* __restrict__ Wout,
        u16* __restrict__ WqkvT, u16* __restrict__ WkvbT, u16* __restrict__ WoutT) {
    int tid = threadIdx.x;
    int bid = blockIdx.x;
    if (bid < 8192) {            // cast: 8192*256 f32x4 = NTOK*HID elems
        int i = bid * 256 + tid;
        f32x4 v = *(const f32x4*)(hs_f + (size_t)i * 4);
        u16 o[4];
        for (int k = 0; k < 4; k++) o[k] = f2b(v[k]);
        *(unsigned long long*)(hs + (size_t)i * 4) = *(unsigned long long*)o;
        return;
    }
    bid -= 8192;
    const float* in; u16* out; int R, C, tilesC;
    if (bid < 1536)      { in = Wq;   out = WqkvT;                       R = HID;  C = NQ;   tilesC = 48; }
    else if (bid < 1920) { bid -= 1536; in = Wkva; out = WqkvT + (size_t)NQ * HID; R = HID; C = 576; tilesC = 12; }
    else if (bid < 2432) { bid -= 1920; in = Wkvb; out = WkvbT;          R = RANK; C = NKVB; tilesC = 64; }
    else                 { bid -= 2432; in = Wout; out = WoutT;          R = HID;  C = HID;  tilesC = 32; }
    __shared__ unsigned int t32[64 * 65];
    int r0 = (bid / tilesC) * 64, c0 = (bid % tilesC) * 64;
    bool valid = (c0 < C);
    for (int i = 0; i < 4; i++) {
        int u = tid + i * 256;
        int rl = u >> 4, c4 = u & 15;
        f32x4 v = {0.f, 0.f, 0.f, 0.f};
        if (valid) v = *(const f32x4*)&in[(size_t)(r0 + rl) * C + c0 + c4 * 4];
        for (int j = 0; j < 4; j++)
            t32[(c4 * 4 + j) * 65 + rl] = f2b(v[j]);
    }
    __syncthreads();
    for (int i = 0; i < 2; i++) {
        int u = tid + i * 256;
        int cl = u >> 3, r8 = (u & 7) * 8;
        unsigned int w[8];
        for (int j = 0; j < 8; j++) w[j] = t32[cl * 65 + r8 + j];
        u32x4 pk;
        for (int j = 0; j < 4; j++) pk[j] = (w[2 * j] & 0xffffu) | (w[2 * j + 1] << 16);
        *(u32x4*)&out[(size_t)(c0 + cl) * R + r0 + r8] = pk;
    }
}

// ---------------- BMx256 / BK=64 / 8-wave dbuf GEMM (T1+T2+T3-lite+T5) ------------
// r9 changes vs r8: (1) T1 XCD-bijective block swizzle on a flattened 1D grid
// (all grids % 8 == 0) -> consecutive chunks (sharing A panels) pinned per-XCD L2;
// (2) staging source offsets precomputed as u32 (hoists the per-tile 64-bit
// base*ld multiplies -> ~6 VALU/tile); (3) bf16 epilogue via v_cvt_pk_bf16_f32
// (halves f2b VALU). Schedule/barriers unchanged (r6/r7-verified).
template <int BM, typename OutT>
__global__ __launch_bounds__(512, 2) void gemm256k(const u16* __restrict__ A,
                                                   const u16* __restrict__ Bt,
                                                   OutT* __restrict__ C,
                                                   int K, int lda, int ldb, int ldc,
                                                   int gx) {
    constexpr int MH = BM / 128;          // A half-tiles per buffer
    constexpr int NHALF = MH + 2;         // total half-tiles per dbuf slot
    __shared__ u16 lds[2 * NHALF][128 * 64];
    int tid = threadIdx.x, lane = tid & 63, w = tid >> 6;
    int wm = w >> 2, wn = w & 3;
    int g = lane >> 4, ln = lane & 15;
    // T1: XCD-bijective swizzle (gridDim.x % 8 == 0 for all our launches)
    int chunk = gridDim.x >> 3;
    int fid = blockIdx.x;
    int sid = (fid & 7) * chunk + (fid >> 3);
    int m0 = (sid / gx) * BM, n0 = (sid % gx) * 256;

    int srow = tid >> 3, schunk = tid & 7;
    int cs = schunk ^ (srow & 7);
    int sdst = tid * 8;

    // precomputed staging source offsets (u32; max index 16.8M < 2^32)
    unsigned int soff[NHALF * 2];
#pragma unroll
    for (int ht = 0; ht < NHALF; ht++) {
        int base = (ht < MH) ? (m0 + ht * 128) : (n0 + (ht - MH) * 128);
        int ld = (ht < MH) ? lda : ldb;
        soff[ht * 2]     = (unsigned)(base + srow) * (unsigned)ld + cs * 8;
        soff[ht * 2 + 1] = (unsigned)(base + 64 + srow) * (unsigned)ld + cs * 8;
    }

    auto stage = [&](int p, int ht, int k0) {
        const u16* src = (ht < MH) ? A : Bt;
        u16* buf = lds[p * NHALF + ht];
        gld_lds16(src + soff[ht * 2] + k0, buf + sdst);
        gld_lds16(src + soff[ht * 2 + 1] + k0, buf + 4096 + sdst);
    };

    int aR = ln * 64;
    int ck0 = ((g ^ (ln & 7)) << 3);
    int ck1 = (((4 + g) ^ (ln & 7)) << 3);
    int bB = (wn & 1) * 4096;
    int aBase = (BM == 256) ? 0 : wm * 4096;

    f32x4 acc[MH * 4][4] = {};
    int NT = K >> 6;

    // prologue: stage tile 0, publish
#pragma unroll
    for (int ht = 0; ht < NHALF; ht++) stage(0, ht, 0);
    __builtin_amdgcn_sched_barrier(0);
    asm volatile("s_waitcnt vmcnt(0)" ::: "memory");
    __builtin_amdgcn_sched_barrier(0);
    __builtin_amdgcn_s_barrier();

    for (int t = 0; t < NT; t++) {
        const u16* Ab = lds[(t & 1) * NHALF + ((BM == 256) ? wm : 0)];
        const u16* Bb = lds[(t & 1) * NHALF + MH + (wn >> 1)];
        int pn = (t & 1) ^ 1;
        bool pf = (t + 1 < NT);
        int k0n = (t + 1) << 6;
        bf16x8 af[4][2], bf[4][2];

        // ---- phase 0: (Mgroup0, Nfrags0-1)
#pragma unroll
        for (int f = 0; f < 4; f++) {
            af[f][0] = lds_frag(&Ab[aBase + f * 1024 + aR + ck0]);
            af[f][1] = lds_frag(&Ab[aBase + f * 1024 + aR + ck1]);
        }
#pragma unroll
        for (int nf = 0; nf < 2; nf++) {
            bf[nf][0] = lds_frag(&Bb[bB + nf * 1024 + aR + ck0]);
            bf[nf][1] = lds_frag(&Bb[bB + nf * 1024 + aR + ck1]);
        }
        if (pf) { stage(pn, 0, k0n); stage(pn, 1, k0n); }
        __builtin_amdgcn_s_barrier();
        __builtin_amdgcn_s_setprio(1);
#pragma unroll
        for (int f = 0; f < 4; f++)
#pragma unroll
            for (int nf = 0; nf < 2; nf++) {
                acc[f][nf] = mfma16(af[f][0], bf[nf][0], acc[f][nf]);
                acc[f][nf] = mfma16(af[f][1], bf[nf][1], acc[f][nf]);
            }
        __builtin_amdgcn_s_setprio(0);

        // ---- phase 1: (Mgroup0, Nfrags2-3)
#pragma unroll
        for (int nf = 2; nf < 4; nf++) {
            bf[nf][0] = lds_frag(&Bb[bB + nf * 1024 + aR + ck0]);
            bf[nf][1] = lds_frag(&Bb[bB + nf * 1024 + aR + ck1]);
        }
        if (pf) {
#pragma unroll
            for (int ht = 2; ht < NHALF; ht++) stage(pn, ht, k0n);
        }
        __builtin_amdgcn_s_barrier();
        __builtin_amdgcn_s_setprio(1);
#pragma unroll
        for (int f = 0; f < 4; f++)
#pragma unroll
            for (int nf = 2; nf < 4; nf++) {
                acc[f][nf] = mfma16(af[f][0], bf[nf][0], acc[f][nf]);
                acc[f][nf] = mfma16(af[f][1], bf[nf][1], acc[f][nf]);
            }
        __builtin_amdgcn_s_setprio(0);

        if constexpr (BM == 256) {
            // ---- phase 2: (Mhalf1, Nfrags0-1)
#pragma unroll
            for (int f = 0; f < 4; f++) {
                af[f][0] = lds_frag(&Ab[(f + 4) * 1024 + aR + ck0]);
                af[f][1] = lds_frag(&Ab[(f + 4) * 1024 + aR + ck1]);
            }
            __builtin_amdgcn_s_barrier();
            __builtin_amdgcn_s_setprio(1);
#pragma unroll
            for (int f = 0; f < 4; f++)
#pragma unroll
                for (int nf = 0; nf < 2; nf++) {
                    acc[f + 4][nf] = mfma16(af[f][0], bf[nf][0], acc[f + 4][nf]);
                    acc[f + 4][nf] = mfma16(af[f][1], bf[nf][1], acc[f + 4][nf]);
                }
            __builtin_amdgcn_s_setprio(0);

            // ---- phase 3: (Mhalf1, Nfrags2-3)
            __builtin_amdgcn_s_barrier();
            __builtin_amdgcn_s_setprio(1);
#pragma unroll
            for (int f = 0; f < 4; f++)
#pragma unroll
                for (int nf = 2; nf < 4; nf++) {
                    acc[f + 4][nf] = mfma16(af[f][0], bf[nf][0], acc[f + 4][nf]);
                    acc[f + 4][nf] = mfma16(af[f][1], bf[nf][1], acc[f + 4][nf]);
                }
            __builtin_amdgcn_s_setprio(0);
        }

        // ---- tile boundary: publish dbuf pn (per-wave drain BEFORE barrier)
        if (pf) {
            __builtin_amdgcn_sched_barrier(0);
            asm volatile("s_waitcnt vmcnt(0)" ::: "memory");
            __builtin_amdgcn_sched_barrier(0);
            __builtin_amdgcn_s_barrier();
        }
    }

    // epilogue: C write (bf16 path packs pairs via v_cvt_pk_bf16_f32)
#pragma unroll
    for (int f = 0; f < MH * 4; f++)
#pragma unroll
        for (int nf = 0; nf < 4; nf++) {
            int mb = m0 + ((BM == 256) ? wm * 128 : wm * 64) + f * 16 + g * 4;
            int n = n0 + wn * 64 + nf * 16 + ln;
            if constexpr (sizeof(OutT) == 2) {
                unsigned int p0, p1;
                asm("v_cvt_pk_bf16_f32 %0, %1, %2" : "=v"(p0)
                    : "v"(acc[f][nf][0]), "v"(acc[f][nf][1]));
                asm("v_cvt_pk_bf16_f32 %0, %1, %2" : "=v"(p1)
                    : "v"(acc[f][nf][2]), "v"(acc[f][nf][3]));
                ((u16*)C)[(size_t)mb * ldc + n]       = (u16)p0;
                ((u16*)C)[(size_t)(mb + 1) * ldc + n] = (u16)(p0 >> 16);
                ((u16*)C)[(size_t)(mb + 2) * ldc + n] = (u16)p1;
                ((u16*)C)[(size_t)(mb + 3) * ldc + n] = (u16)(p1 >> 16);
            } else {
#pragma unroll
                for (int r = 0; r < 4; r++)
                    store_out(&C[(size_t)(mb + r) * ldc + n], acc[f][nf][r]);
            }
        }
}

// ---------------- fused RoPE(q) + LayerNorm(kv_a) — disjoint qkv columns ----------
__global__ void rope_ln(u16* __restrict__ qkv, const float* __restrict__ freqs,
                        const float* __restrict__ gamma, const float* __restrict__ beta,
                        u16* __restrict__ kv_c) {
    int token = blockIdx.x;
    int s = token & (SEQ - 1);
    int tid = threadIdx.x;
    // --- RoPE on q (cols h*DQK+128..h*DQK+192): 512 pairs
    for (int i = 0; i < 2; i++) {
        int idx = tid + i * 256;
        int hh = idx >> 5, p = idx & 31;
        float th = freqs[s * 32 + p];
        float c = __cosf(th), sn = __sinf(th);
        size_t off = (size_t)token * NQKV + hh * DQK + DN + 2 * p;
        float x1 = b2f(qkv[off]), x2 = b2f(qkv[off + 1]);
        qkv[off]     = f2b(x1 * c - x2 * sn);
        qkv[off + 1] = f2b(x1 * sn + x2 * c);
    }
    // --- LayerNorm over cols NQ..NQ+511 (independent of the RoPE region)
    size_t base = (size_t)token * NQKV + NQ;
    float x0 = b2f(qkv[base + tid]), x1 = b2f(qkv[base + 256 + tid]);
    float sm = x0 + x1, q2 = x0 * x0 + x1 * x1;
    for (int o = 32; o > 0; o >>= 1) { sm += __shfl_xor(sm, o); q2 += __shfl_xor(q2, o); }
    __shared__ float sh[8];
    int lane = tid & 63, w = tid >> 6;
    if (lane == 0) { sh[w] = sm; sh[4 + w] = q2; }
    __syncthreads();
    float S = sh[0] + sh[1] + sh[2] + sh[3];
    float Q2 = sh[4] + sh[5] + sh[6] + sh[7];
    float mu = S * (1.f / 512.f);
    float var = Q2 * (1.f / 512.f) - mu * mu;
    float rs = rsqrtf(var + 1e-5f);
    kv_c[(size_t)token * RANK + tid] =
        f2b((x0 - mu) * rs * gamma[tid] + beta[tid]);
    kv_c[(size_t)token * RANK + 256 + tid] =
        f2b((x1 - mu) * rs * gamma[256 + tid] + beta[256 + tid]);
}

// ---------------- fused K assembly + V transpose (block-id split) -----------------
__global__ void kv_prep(const u16* __restrict__ kvb, const u16* __restrict__ qkv,
                        const float* __restrict__ freqs, u16* __restrict__ Kf,
                        u16* __restrict__ Vt) {
    __shared__ unsigned int t32[64 * 65];
    int bid = blockIdx.x;
    int tid = threadIdx.x;
    if (bid < NTOK) {
        int token = bid;
        int b = token >> 11;
        int s = token & (SEQ - 1);
        u16* roped = (u16*)t32;
        if (tid < 32) {
            int p = tid;
            float th = freqs[s * 32 + p];
            float c = __cosf(th), sn = __sinf(th);
            float x1 = b2f(qkv[(size_t)token * NQKV + NQ + RANK + 2 * p]);
            float x2 = b2f(qkv[(size_t)token * NQKV + NQ + RANK + 2 * p + 1]);
            roped[2 * p]     = f2b(x1 * c - x2 * sn);
            roped[2 * p + 1] = f2b(x1 * sn + x2 * c);
        }
        __syncthreads();
        int kt = s >> 6, r = s & 63;
        int swr = ((r >> 1) & 3) * 8;
        {   // k_nope
            int hh = tid >> 4, c8 = (tid & 15) * 8;
            size_t dst = ((size_t)(b * NH + hh) * 32 + kt) * 12288
                       + (size_t)(c8 >> 5) * 2048 + r * 32 + ((c8 & 31) ^ swr);
            *(u32x4*)&Kf[dst] = *(const u32x4*)&kvb[(size_t)token * NKVB + hh * 256 + c8];
        }
        if (tid < 128) {  // rope broadcast
            int hh = tid >> 3, c8 = (tid & 7) * 8;
            size_t dst = ((size_t)(b * NH + hh) * 32 + kt) * 12288
                       + (size_t)(4 + (c8 >> 5)) * 2048 + r * 32 + ((c8 & 31) ^ swr);
            *(u32x4*)&Kf[dst] = *(u32x4*)&roped[c8];
        }
        return;
    }
    // ---- V transpose part
    int rblk = bid - NTOK;                 // [0, 2048)
    int bx = rblk & 31;                    // s-tile
    int by = (rblk >> 5) & 1;              // d-tile
    int bz = rblk >> 6;                    // b*NH+h
    int st = bx * 64, dt = by * 64;
    int b = bz >> 4, h = bz & 15;
    for (int i = 0; i < 2; i++) {
        int u = tid + i * 256;
        int sl = u >> 3, c8 = (u & 7) * 8;
        u32x4 v = *(const u32x4*)&kvb[((size_t)(b * SEQ + st + sl) * NH + h) * 256 + DN + dt + c8];
        for (int j = 0; j < 4; j++) {
            t32[(c8 + 2 * j) * 65 + sl]     = v[j] & 0xffffu;
            t32[(c8 + 2 * j + 1) * 65 + sl] = v[j] >> 16;
        }
    }
    __syncthreads();
    for (int i = 0; i < 2; i++) {
        int u = tid + i * 256;
        int dl = u >> 3, s8 = (u & 7) * 8;
        unsigned int w[8];
        for (int j = 0; j < 8; j++) w[j] = t32[dl * 65 + s8 + j];
        u32x4 pk;
        for (int j = 0; j < 4; j++) pk[j] = (w[2 * j] & 0xffffu) | (w[2 * j + 1] << 16);
        size_t dst = ((size_t)(b * NH + h) * 32 + bx) * 8192
                   + (size_t)(s8 >> 5) * 4096 + (size_t)(dt + dl) * 32 + (s8 & 31);
        *(u32x4*)&Vt[dst] = pk;
    }
}

// ---------------- flash attention (r6-exact: 141 us verified) ---------------------
#define KC    64
#define QTILE 64
#define NIT  (SEQ / KC)
__global__ __launch_bounds__(256, 4) void attn_kernel(const u16* __restrict__ Q,
                                                      const u16* __restrict__ Kf,
                                                      const u16* __restrict__ Vt,
                                                      u16* __restrict__ O) {
    __shared__ u16 Ks[6 * 64 * 32];      // 24 KB swizzled K tile
    __shared__ u16 Ps[2][QTILE * 64];    // 16 KB double-buffered P (XOR-swizzled)
    int tid = threadIdx.x, lane = tid & 63, w = tid >> 6;
    int w1 = w & 1;    // q 32-half
    int w2 = w >> 1;   // kv 32-half (QK) / d 64-half (PV)
    int g = lane >> 4, ln = lane & 15;
    int bid = blockIdx.x;
    int swz = ((bid & 7) << 7) | (bid >> 3);
    int qt = swz & 31, h = (swz >> 5) & 15, b = swz >> 9;

    size_t qbase = ((size_t)(b * SEQ + qt * QTILE)) * NQKV + h * DQK;
    const u16* Kh = Kf + (size_t)(b * NH + h) * (32 * 12288);
    const u16* Vh = Vt + (size_t)(b * NH + h) * (32 * 8192);

    // Q fragments -> pinned registers (opaque asm loads, no remat possible)
    u32x4 qreg[2][6];
#pragma unroll
    for (int ni = 0; ni < 2; ni++)
#pragma unroll
        for (int kk = 0; kk < 6; kk++) {
            const u16* qp = &Q[qbase + (size_t)(w1 * 32 + ni * 16 + ln) * NQKV + kk * 32 + g * 8];
            asm volatile("global_load_dwordx4 %0, %1, off"
                         : "=v"(qreg[ni][kk]) : "v"(qp));
        }
    // stage K tile 0 (linear DMA copy of pre-swizzled global image)
#pragma unroll
    for (int i = 0; i < 6; i++)
        gld_lds16(&Kh[i * 2048 + tid * 8], &Ks[i * 2048 + tid * 8]);

    int kRd0 = (w2 * 32 + ln) * 64 + ((g * 16) ^ (((ln >> 1) & 3) << 4));  // bytes
    int kRd1 = kRd0 + 16 * 64;
    int vrow = w2 * 2048 + ln * 32 + g * 8;   // u16, + kk*4096 + ni*512
    int pswz = (ln & 7) << 4;

    f32x4 oacc[2][4] = {};
    float lpriv[2] = {0.f, 0.f};

    for (int kt = 0; kt < NIT; kt++) {
        asm volatile("s_waitcnt vmcnt(0)" ::: "memory");
        __builtin_amdgcn_sched_barrier(0);
        __syncthreads();                   // K(kt) visible to all waves
        const char* KsB = (const char*)Ks;
        f32x4 sacc[2][2] = {};
#pragma unroll
        for (int kk = 0; kk < 6; kk++) {
            bf16x8 af0 = lds_frag((const u16*)(KsB + kk * 4096 + kRd0));
            bf16x8 af1 = lds_frag((const u16*)(KsB + kk * 4096 + kRd1));
            bf16x8 q0 = to_frag(qreg[0][kk]), q1 = to_frag(qreg[1][kk]);
            sacc[0][0] = mfma16(af0, q0, sacc[0][0]);
            sacc[0][1] = mfma16(af0, q1, sacc[0][1]);
            sacc[1][0] = mfma16(af1, q0, sacc[1][0]);
            sacc[1][1] = mfma16(af1, q1, sacc[1][1]);
        }
        char* Pb = (char*)Ps[kt & 1];
#pragma unroll
        for (int mi = 0; mi < 2; mi++)
#pragma unroll
            for (int ni = 0; ni < 2; ni++) {
                float p0 = exp2f(sacc[mi][ni][0] * SCALE_LOG2E);
                float p1 = exp2f(sacc[mi][ni][1] * SCALE_LOG2E);
                float p2 = exp2f(sacc[mi][ni][2] * SCALE_LOG2E);
                float p3 = exp2f(sacc[mi][ni][3] * SCALE_LOG2E);
                lpriv[ni] += (p0 + p1) + (p2 + p3);
                unsigned int c0, c1;
                asm("v_cvt_pk_bf16_f32 %0, %1, %2" : "=v"(c0) : "v"(p0), "v"(p1));
                asm("v_cvt_pk_bf16_f32 %0, %1, %2" : "=v"(c1) : "v"(p2), "v"(p3));
                uint2 pk; pk.x = c0; pk.y = c1;
                int pwB = (w1 * 32 + ni * 16 + ln) * 128
                        + ((w2 * 64 + mi * 32 + g * 8) ^ pswz);
                *(uint2*)(Pb + pwB) = pk;
            }
        __syncthreads();                   // P(kt) ready; K(kt) reads done
        if (kt + 1 < NIT) {
            const u16* kT = Kh + (size_t)(kt + 1) * 12288;
#pragma unroll
            for (int i = 0; i < 6; i++)
                gld_lds16(&kT[i * 2048 + tid * 8], &Ks[i * 2048 + tid * 8]);
        }
        const u16* vT = Vh + (size_t)kt * 8192;
#pragma unroll
        for (int kk = 0; kk < 2; kk++) {
            bf16x8 pa[2], vb[4];
#pragma unroll
            for (int mi = 0; mi < 2; mi++)
                pa[mi] = lds_frag((const u16*)(Pb + (w1 * 32 + mi * 16 + ln) * 128
                                               + ((kk * 64 + g * 16) ^ pswz)));
#pragma unroll
            for (int ni = 0; ni < 4; ni++)
                vb[ni] = to_frag(*(const u32x4*)&vT[kk * 4096 + ni * 512 + vrow]);
#pragma unroll
            for (int mi = 0; mi < 2; mi++)
#pragma unroll
                for (int ni = 0; ni < 4; ni++)
                    oacc[mi][ni] = mfma16(pa[mi], vb[ni], oacc[mi][ni]);
        }
    }

    float* lsumF = (float*)Ps[0];
    for (int ni = 0; ni < 2; ni++) {
        float v = lpriv[ni];
        v += __shfl_xor(v, 16);
        v += __shfl_xor(v, 32);
        if (g == 0) lsumF[w2 * 64 + w1 * 32 + ni * 16 + ln] = v;
    }
    __syncthreads();
    for (int mi = 0; mi < 2; mi++)
        for (int ni = 0; ni < 4; ni++) {
            int d = w2 * 64 + ni * 16 + ln;
            for (int r = 0; r < 4; r++) {
                int row = w1 * 32 + mi * 16 + g * 4 + r;
                float l = lsumF[row] + lsumF[64 + row];
                O[((size_t)(b * SEQ + qt * QTILE + row) * NH + h) * DV + d] =
                    f2b(oacc[mi][ni][r] / l);
            }
        }
}

// ---------------- launcher ----------------
extern "C" void kernel_launch(void* const* d_in, const int* in_sizes, int n_in,
                              void* d_out, int out_size, void* d_ws, size_t ws_size,
                              hipStream_t stream) {
    const float* hs_f  = (const float*)d_in[0];
    const float* freqs = (const float*)d_in[1];
    const float* Wq    = (const float*)d_in[2];
    const float* Wkva  = (const float*)d_in[3];
    const float* gamma = (const float*)d_in[4];
    const float* beta  = (const float*)d_in[5];
    const float* Wkvb  = (const float*)d_in[6];
    const float* Wout  = (const float*)d_in[7];
    float* outp = (float*)d_out;

    char* ws = (char*)d_ws;
    size_t off = 0;
    auto alloc = [&](size_t elems) -> u16* {
        u16* p = (u16*)(ws + off);
        off += ((elems * 2 + 255) / 256) * 256;
        return p;
    };
    u16* hs     = alloc((size_t)NTOK * HID);
    u16* WqkvT  = alloc((size_t)NQKV * HID);
    u16* WkvbT  = alloc((size_t)NKVB * RANK);
    u16* WoutT  = alloc((size_t)HID * HID);
    u16* qkv    = alloc((size_t)NTOK * NQKV);
    u16* kv_c   = alloc((size_t)NTOK * RANK);
    u16* kvb    = alloc((size_t)NTOK * NKVB);
    u16* Kf     = alloc((size_t)NTOK * NQ);
    u16* Vt     = alloc((size_t)BATCH * NH * DV * SEQ);
    u16* attn   = alloc((size_t)NTOK * NH * DV);
    (void)ws_size; (void)in_sizes; (void)n_in; (void)out_size;

    // 1. fused prep: cast + all weight transposes
    prep_kernel<<<8192 + 1536 + 384 + 512 + 1024, 256, 0, stream>>>(
        hs_f, hs, Wq, Wkva, Wkvb, Wout, WqkvT, WkvbT, WoutT);

    // 2. fused q + kv_a GEMM: (4096 x 3840 x 2048), flattened 1D grid 240 (%8==0)
    gemm256k<256><<<(NQKV / 256) * (NTOK / 256), 512, 0, stream>>>(
        hs, WqkvT, qkv, HID, HID, HID, NQKV, NQKV / 256);

    // 3. fused RoPE(q) + LayerNorm(kv_a)
    rope_ln<<<NTOK, 256, 0, stream>>>(qkv, freqs, gamma, beta, kv_c);

    // 4. kvb = kv_c @ Wkv_b (4096 x 4096 x 512), grid 256 (%8==0)
    gemm256k<256><<<(NKVB / 256) * (NTOK / 256), 512, 0, stream>>>(
        kv_c, WkvbT, kvb, RANK, RANK, RANK, NKVB, NKVB / 256);

    // 5. fused K assembly + V transpose
    kv_prep<<<NTOK + 2048, 256, 0, stream>>>(kvb, qkv, freqs, Kf, Vt);

    // 6. attention (r6-exact kernel)
    attn_kernel<<<1024, 256, 0, stream>>>(qkv, Kf, Vt, attn);

    // 7. out = attn @ Wout (4096 x 2048 x 2048), BM=128, grid 256 (%8==0)
    gemm256k<128><<<(HID / 256) * (NTOK / 128), 512, 0, stream>>>(
        attn, WoutT, outp, HID, HID, HID, HID, HID / 256);
}